// Round 7
// baseline (451.181 us; speedup 1.0000x reference)
//
#include <hip/hip_runtime.h>

#define HDIM 128
#define NGRAPH 64
#define INVSTD 0.99999500003749972f   // 1/sqrt(1+1e-5)

typedef unsigned short ushort_t;
typedef unsigned int uint_t;
typedef unsigned char uchar_t;
typedef __attribute__((ext_vector_type(8))) short bf16x8;   // 8 bf16 = 4 VGPR
typedef __attribute__((ext_vector_type(4))) float f32x4;
typedef __attribute__((ext_vector_type(2))) float f32x2;

__device__ __forceinline__ float bf2f(uint_t u) {            // low 16 bits = bf16
    return __int_as_float((int)(u << 16));
}
__device__ __forceinline__ float bf2f_hi(uint_t u) {         // high 16 bits = bf16
    return __int_as_float((int)(u & 0xFFFF0000u));
}
__device__ __forceinline__ uint_t f2bf(float f) {            // RNE
    uint_t x = __float_as_uint(f);
    return (x + 0x7FFFu + ((x >> 16) & 1u)) >> 16;
}
__device__ __forceinline__ uint_t pack2(float a, float b) {
    return f2bf(a) | (f2bf(b) << 16);
}
__device__ __forceinline__ uint_t pack4fp8(float a, float b, float c, float d) {
    int v = __builtin_amdgcn_cvt_pk_fp8_f32(a, b, 0, false);
    v = __builtin_amdgcn_cvt_pk_fp8_f32(c, d, v, true);
    return (uint_t)v;
}

// ---------------- encode: hb=bf16(h), hq=fp8(h);  h = x*ew + eb ----------------
__global__ void k_encode(const float* __restrict__ x, const float* __restrict__ ew,
                         const float* __restrict__ eb, ushort_t* __restrict__ hb,
                         uchar_t* __restrict__ hq, int N) {
    int tid = blockIdx.x * blockDim.x + threadIdx.x;
    int stride = gridDim.x * blockDim.x;
    int q = tid & 15;
    float4 wa = ((const float4*)ew)[2 * q];
    float4 wb = ((const float4*)ew)[2 * q + 1];
    float4 ba = ((const float4*)eb)[2 * q];
    float4 bb = ((const float4*)eb)[2 * q + 1];
    int total = N * 16;
    for (int t = tid; t < total; t += stride) {
        int n = t >> 4;
        float xv = x[n];
        float v0 = fmaf(xv, wa.x, ba.x), v1 = fmaf(xv, wa.y, ba.y);
        float v2 = fmaf(xv, wa.z, ba.z), v3 = fmaf(xv, wa.w, ba.w);
        float v4 = fmaf(xv, wb.x, bb.x), v5 = fmaf(xv, wb.y, bb.y);
        float v6 = fmaf(xv, wb.z, bb.z), v7 = fmaf(xv, wb.w, bb.w);
        uint4 o;
        o.x = pack2(v0, v1); o.y = pack2(v2, v3);
        o.z = pack2(v4, v5); o.w = pack2(v6, v7);
        ((uint4*)(hb + (size_t)n * HDIM))[q] = o;
        uint2 o8;
        o8.x = pack4fp8(v0, v1, v2, v3);
        o8.y = pack4fp8(v4, v5, v6, v7);
        ((uint2*)(hq + (size_t)n * HDIM))[q] = o8;
    }
}

// ---------------- CSR build ----------------
__global__ void k_hist(const int* __restrict__ ei, int* deg, int* __restrict__ rank_, int E) {
    int e = blockIdx.x * 256 + threadIdx.x;
    if (e < E) {
        int d = ei[E + e];
        rank_[e] = atomicAdd(&deg[d], 1);
    }
}

__global__ void k_scan1(const int* __restrict__ deg, int* rs, int* bsum, int N) {
    __shared__ int sm[256];
    int gid = blockIdx.x * 256 + threadIdx.x;
    int v = (gid < N) ? deg[gid] : 0;
    sm[threadIdx.x] = v;
    __syncthreads();
    #pragma unroll
    for (int off = 1; off < 256; off <<= 1) {
        int t = (threadIdx.x >= off) ? sm[threadIdx.x - off] : 0;
        __syncthreads();
        sm[threadIdx.x] += t;
        __syncthreads();
    }
    if (gid < N) rs[gid] = sm[threadIdx.x] - v;
    if (threadIdx.x == 255) bsum[blockIdx.x] = sm[255];
}

__global__ void k_scan2(int* bsum, int nb) {
    __shared__ int sm[512];
    int t = threadIdx.x;
    int v = (t < nb) ? bsum[t] : 0;
    sm[t] = v;
    __syncthreads();
    #pragma unroll
    for (int off = 1; off < 512; off <<= 1) {
        int u = (t >= off) ? sm[t - off] : 0;
        __syncthreads();
        sm[t] += u;
        __syncthreads();
    }
    if (t < nb) bsum[t] = sm[t] - v;
}

__global__ void k_scan3(int* rs, const int* __restrict__ bsum, int N, int E) {
    int gid = blockIdx.x * 256 + threadIdx.x;
    if (gid < N) rs[gid] += bsum[gid >> 8];
    if (gid == N) rs[N] = E;
}

__global__ void k_scatter(const int* __restrict__ ei, const float* __restrict__ attr,
                          const int* __restrict__ rs, const int* __restrict__ rank_,
                          int2* __restrict__ epack, int E) {
    int e = blockIdx.x * 256 + threadIdx.x;
    if (e < E) {
        int s = ei[e], d = ei[E + e];
        int p = rs[d] + rank_[e];
        epack[p] = make_int2(s, __float_as_int(attr[e]));
    }
}

// ------- aggregation: 8 lanes/edge, fp8 uint4 gathers, 2 chains -------
// zb[n] = bf16( (1+eps)*hb[n] + sum_e relu(hq[src_e] + a_e*ew + eb) )
__device__ __forceinline__ void acc_e(float acc[16], const uint4& u, float at,
                                      const float* w, const float* b) {
    const uint_t uu[4] = {u.x, u.y, u.z, u.w};
    #pragma unroll
    for (int i = 0; i < 4; ++i) {
        f32x2 lo = __builtin_amdgcn_cvt_pk_f32_fp8(uu[i], false);
        f32x2 hi = __builtin_amdgcn_cvt_pk_f32_fp8(uu[i], true);
        acc[4*i+0] += fmaxf(lo[0] + fmaf(at, w[4*i+0], b[4*i+0]), 0.f);
        acc[4*i+1] += fmaxf(lo[1] + fmaf(at, w[4*i+1], b[4*i+1]), 0.f);
        acc[4*i+2] += fmaxf(hi[0] + fmaf(at, w[4*i+2], b[4*i+2]), 0.f);
        acc[4*i+3] += fmaxf(hi[1] + fmaf(at, w[4*i+3], b[4*i+3]), 0.f);
    }
}

__global__ __launch_bounds__(256) void k_agg(
    const uchar_t* __restrict__ hq, const ushort_t* __restrict__ hb,
    const int* __restrict__ rs, const int2* __restrict__ epack,
    const float* __restrict__ ew, const float* __restrict__ eb,
    const float* __restrict__ epsp, ushort_t* __restrict__ zb, int N) {
    int wave = (blockIdx.x * 256 + threadIdx.x) >> 6;
    if (wave >= N) return;
    int lane = threadIdx.x & 63;
    int p = lane >> 3;          // edge slot 0..7
    int q = lane & 7;           // features 16q .. 16q+15
    int n = wave;
    int beg = rs[n];
    int cntE = rs[n + 1] - beg;
    float w[16], b[16];
    #pragma unroll
    for (int i = 0; i < 4; ++i) {
        float4 t1 = ((const float4*)ew)[q * 4 + i];
        float4 t2 = ((const float4*)eb)[q * 4 + i];
        w[4*i+0] = t1.x; w[4*i+1] = t1.y; w[4*i+2] = t1.z; w[4*i+3] = t1.w;
        b[4*i+0] = t2.x; b[4*i+1] = t2.y; b[4*i+2] = t2.z; b[4*i+3] = t2.w;
    }
    float acc[16], acc2[16];
    #pragma unroll
    for (int k = 0; k < 16; ++k) { acc[k] = 0.f; acc2[k] = 0.f; }

    int j = p;
    for (; j + 8 < cntE; j += 16) {
        int2 e1 = epack[beg + j];
        int2 e2 = epack[beg + j + 8];
        uint4 u1 = *(const uint4*)(hq + (size_t)e1.x * HDIM + q * 16);
        uint4 u2 = *(const uint4*)(hq + (size_t)e2.x * HDIM + q * 16);
        acc_e(acc,  u1, __int_as_float(e1.y), w, b);
        acc_e(acc2, u2, __int_as_float(e2.y), w, b);
    }
    if (j < cntE) {
        int2 e1 = epack[beg + j];
        uint4 u1 = *(const uint4*)(hq + (size_t)e1.x * HDIM + q * 16);
        acc_e(acc, u1, __int_as_float(e1.y), w, b);
    }
    #pragma unroll
    for (int k = 0; k < 16; ++k) {
        float v = acc[k] + acc2[k];
        v += __shfl_xor(v, 8);
        v += __shfl_xor(v, 16);
        v += __shfl_xor(v, 32);
        acc[k] = v;
    }
    if (p == 0) {
        float sc = 1.f + epsp[0];
        uint4 s0 = *(const uint4*)(hb + (size_t)n * HDIM + q * 16);
        uint4 s1 = *(const uint4*)(hb + (size_t)n * HDIM + q * 16 + 8);
        float h[16];
        h[0] = bf2f(s0.x); h[1] = bf2f_hi(s0.x);
        h[2] = bf2f(s0.y); h[3] = bf2f_hi(s0.y);
        h[4] = bf2f(s0.z); h[5] = bf2f_hi(s0.z);
        h[6] = bf2f(s0.w); h[7] = bf2f_hi(s0.w);
        h[8] = bf2f(s1.x); h[9] = bf2f_hi(s1.x);
        h[10] = bf2f(s1.y); h[11] = bf2f_hi(s1.y);
        h[12] = bf2f(s1.z); h[13] = bf2f_hi(s1.z);
        h[14] = bf2f(s1.w); h[15] = bf2f_hi(s1.w);
        uint4 o0, o1;
        o0.x = pack2(fmaf(sc, h[0], acc[0]),  fmaf(sc, h[1], acc[1]));
        o0.y = pack2(fmaf(sc, h[2], acc[2]),  fmaf(sc, h[3], acc[3]));
        o0.z = pack2(fmaf(sc, h[4], acc[4]),  fmaf(sc, h[5], acc[5]));
        o0.w = pack2(fmaf(sc, h[6], acc[6]),  fmaf(sc, h[7], acc[7]));
        o1.x = pack2(fmaf(sc, h[8], acc[8]),  fmaf(sc, h[9], acc[9]));
        o1.y = pack2(fmaf(sc, h[10], acc[10]), fmaf(sc, h[11], acc[11]));
        o1.z = pack2(fmaf(sc, h[12], acc[12]), fmaf(sc, h[13], acc[13]));
        o1.w = pack2(fmaf(sc, h[14], acc[14]), fmaf(sc, h[15], acc[15]));
        *(uint4*)(zb + (size_t)n * HDIM + q * 16) = o0;
        *(uint4*)(zb + (size_t)n * HDIM + q * 16 + 8) = o1;
    }
}

// ------------- MFMA GEMM: out = epilogue(A @ W + bias), all [*,128] -------------
// MODE 0: relu; MODE 1: BN+relu.  WQ 1: also write fp8 copy outq.
#define WTPAD 136
template<int MODE, int WQ>
__global__ __launch_bounds__(256) void k_gemm(
    const ushort_t* __restrict__ A, const float* __restrict__ W,
    const float* __restrict__ bias, const float* __restrict__ gam,
    const float* __restrict__ bet, ushort_t* __restrict__ out,
    uchar_t* __restrict__ outq, int N) {
    __shared__ ushort_t wt[128 * WTPAD];        // wt[n][k] = bf16(W[k][n])
    int tid = threadIdx.x;
    #pragma unroll
    for (int i = 0; i < 64; ++i) {
        int idx = i * 256 + tid;
        int k = idx >> 7, n = idx & 127;
        wt[n * WTPAD + k] = (ushort_t)f2bf(W[idx]);
    }
    __syncthreads();

    int wid = tid >> 6, lane = tid & 63;
    int ra = lane & 15, qa = lane >> 4;

    bf16x8 bfr[4][8];
    #pragma unroll
    for (int ks = 0; ks < 4; ++ks)
        #pragma unroll
        for (int nf = 0; nf < 8; ++nf)
            bfr[ks][nf] = *(const bf16x8*)&wt[(nf * 16 + ra) * WTPAD + ks * 32 + qa * 8];

    float bi[8], gg[8], be[8];
    #pragma unroll
    for (int nf = 0; nf < 8; ++nf) {
        int col = nf * 16 + ra;
        bi[nf] = bias[col];
        if (MODE == 1) { gg[nf] = gam[col]; be[nf] = bet[col]; }
    }

    bf16x8 azero;
    #pragma unroll
    for (int j = 0; j < 8; ++j) azero[j] = 0;

    #pragma unroll
    for (int it = 0; it < 2; ++it) {
        int m0 = blockIdx.x * 128 + it * 64 + wid * 16;
        int mr = m0 + ra;
        bf16x8 afr[4];
        #pragma unroll
        for (int ks = 0; ks < 4; ++ks)
            afr[ks] = (mr < N) ? *(const bf16x8*)&A[(size_t)mr * HDIM + ks * 32 + qa * 8]
                               : azero;
        f32x4 acc[8];
        #pragma unroll
        for (int nf = 0; nf < 8; ++nf)
            #pragma unroll
            for (int j = 0; j < 4; ++j) acc[nf][j] = 0.f;
        #pragma unroll
        for (int ks = 0; ks < 4; ++ks)
            #pragma unroll
            for (int nf = 0; nf < 8; ++nf)
                acc[nf] = __builtin_amdgcn_mfma_f32_16x16x32_bf16(afr[ks], bfr[ks][nf], acc[nf], 0, 0, 0);
        #pragma unroll
        for (int nf = 0; nf < 8; ++nf) {
            #pragma unroll
            for (int r = 0; r < 4; ++r) {
                int row = m0 + qa * 4 + r;
                if (row < N) {
                    float v = acc[nf][r] + bi[nf];
                    if (MODE == 0) v = fmaxf(v, 0.f);
                    else           v = fmaxf(fmaf(gg[nf] * v, INVSTD, be[nf]), 0.f);
                    out[(size_t)row * HDIM + nf * 16 + ra] = (ushort_t)f2bf(v);
                    if (WQ)
                        outq[(size_t)row * HDIM + nf * 16 + ra] =
                            (uchar_t)(__builtin_amdgcn_cvt_pk_fp8_f32(v, 0.f, 0, false) & 0xFF);
                }
            }
        }
    }
}

// ------------- pooling: segmented reduction over sorted batch (bf16 in) -------------
#define PCHUNK 256
#define PWIN 4
__global__ __launch_bounds__(256) void k_pool2(const ushort_t* __restrict__ hb,
                                               const int* __restrict__ batch,
                                               float* pooled, int N) {
    __shared__ float acc[PWIN][HDIM];
    int n0 = blockIdx.x * PCHUNK;
    if (n0 >= N) return;
    int n1 = min(n0 + PCHUNK, N);
    int g0 = batch[n0];
    int g1 = batch[n1 - 1];
    for (int i = threadIdx.x; i < PWIN * HDIM; i += 256) ((float*)acc)[i] = 0.f;
    __syncthreads();

    int grp = threadIdx.x >> 5;
    int q = threadIdx.x & 31;
    float4 racc = make_float4(0.f, 0.f, 0.f, 0.f);
    int gcur = g0;
    for (int n = n0 + grp; n < n1; n += 8) {
        int g = batch[n];
        if (g != gcur) {
            int w = gcur - g0;
            float* p = (w < PWIN) ? &acc[w][q * 4] : (pooled + gcur * HDIM + q * 4);
            atomicAdd(p + 0, racc.x); atomicAdd(p + 1, racc.y);
            atomicAdd(p + 2, racc.z); atomicAdd(p + 3, racc.w);
            racc = make_float4(0.f, 0.f, 0.f, 0.f);
            gcur = g;
        }
        uint2 u = ((const uint2*)(hb + (size_t)n * HDIM))[q];
        racc.x += bf2f(u.x);
        racc.y += bf2f_hi(u.x);
        racc.z += bf2f(u.y);
        racc.w += bf2f_hi(u.y);
    }
    {
        int w = gcur - g0;
        float* p = (w < PWIN) ? &acc[w][q * 4] : (pooled + gcur * HDIM + q * 4);
        atomicAdd(p + 0, racc.x); atomicAdd(p + 1, racc.y);
        atomicAdd(p + 2, racc.z); atomicAdd(p + 3, racc.w);
    }
    __syncthreads();

    int span = min(g1 - g0 + 1, PWIN);
    for (int i = threadIdx.x; i < span * HDIM; i += 256) {
        int w = i >> 7, f = i & 127;
        float v = acc[w][f];
        if (v != 0.f) atomicAdd(pooled + (g0 + w) * HDIM + f, v);
    }
}

// ------------- classifier (count fused via binary search) -------------
__global__ void k_classify(const float* __restrict__ pooled, const int* __restrict__ batch,
                           const float* __restrict__ cw1, const float* __restrict__ cb1,
                           const float* __restrict__ cw2, const float* __restrict__ cb2,
                           float* __restrict__ out, int N) {
    __shared__ float p[HDIM];
    int g = blockIdx.x, j = threadIdx.x;
    int lo = 0, hi = N;
    while (lo < hi) { int m = (lo + hi) >> 1; if (batch[m] < g) lo = m + 1; else hi = m; }
    int lo2 = lo, hi2 = N;
    while (lo2 < hi2) { int m = (lo2 + hi2) >> 1; if (batch[m] < g + 1) lo2 = m + 1; else hi2 = m; }
    float c = fmaxf((float)(lo2 - lo), 1.f);
    p[j]      = pooled[g * HDIM + j] / c;
    p[j + 64] = pooled[g * HDIM + j + 64] / c;
    __syncthreads();
    float acc = cb1[j];
    #pragma unroll 4
    for (int k = 0; k < HDIM; ++k) acc = fmaf(p[k], cw1[k * 64 + j], acc);
    acc = fmaxf(acc, 0.f);
    float v = acc * cw2[j];
    #pragma unroll
    for (int off = 32; off > 0; off >>= 1) v += __shfl_down(v, off, 64);
    if (j == 0) out[g] = 1.f / (1.f + expf(-(v + cb2[0])));
}

static inline size_t align_up(size_t v, size_t a) { return (v + a - 1) & ~(a - 1); }

extern "C" void kernel_launch(void* const* d_in, const int* in_sizes, int n_in,
                              void* d_out, int out_size, void* d_ws, size_t ws_size,
                              hipStream_t stream) {
    const float* x      = (const float*)d_in[0];
    const int*   ei     = (const int*)d_in[1];
    const float* eattr  = (const float*)d_in[2];
    const int*   batch  = (const int*)d_in[3];
    const float* enc_w  = (const float*)d_in[4];
    const float* enc_b  = (const float*)d_in[5];
    const float* eenc_w = (const float*)d_in[6];
    const float* eenc_b = (const float*)d_in[7];
    const float* eps    = (const float*)d_in[8];
    const float* w1     = (const float*)d_in[9];
    const float* b1     = (const float*)d_in[10];
    const float* w2     = (const float*)d_in[11];
    const float* b2     = (const float*)d_in[12];
    const float* gamma  = (const float*)d_in[13];
    const float* beta   = (const float*)d_in[14];
    const float* cw1    = (const float*)d_in[15];
    const float* cb1    = (const float*)d_in[16];
    const float* cw2    = (const float*)d_in[17];
    const float* cb2    = (const float*)d_in[18];

    int N = in_sizes[0];          // 100000
    int E = in_sizes[2];          // 1600000

    char* wsb = (char*)d_ws;
    size_t off = 0;
    ushort_t* hb  = (ushort_t*)(wsb + off); off = align_up(off + (size_t)N * HDIM * 2, 256);
    uchar_t*  hq  = (uchar_t*)(wsb + off);  off = align_up(off + (size_t)N * HDIM, 256);
    ushort_t* zb  = (ushort_t*)(wsb + off); off = align_up(off + (size_t)N * HDIM * 2, 256);
    float* pooled = (float*)(wsb + off);    off = align_up(off + NGRAPH * HDIM * 4, 256);
    int*   deg    = (int*)(wsb + off);      off = align_up(off + (size_t)N * 4, 256);
    int*   rs     = (int*)(wsb + off);      off = align_up(off + (size_t)(N + 1) * 4, 256);
    int*   rank_  = (int*)(wsb + off);      off = align_up(off + (size_t)E * 4, 256);
    int*   bsum   = (int*)(wsb + off);      off = align_up(off + 2048 * 4, 256);
    int2*  epack  = (int2*)(wsb + off);     off = align_up(off + (size_t)E * 8, 256);

    int nb = (N + 255) / 256;
    int eb_blocks = (E + 255) / 256;

    // CSR build
    hipMemsetAsync(deg, 0, (size_t)N * 4, stream);
    k_hist<<<eb_blocks, 256, 0, stream>>>(ei, deg, rank_, E);
    k_scan1<<<nb, 256, 0, stream>>>(deg, rs, bsum, N);
    k_scan2<<<1, 512, 0, stream>>>(bsum, nb);
    k_scan3<<<(N + 256) / 256, 256, 0, stream>>>(rs, bsum, N, E);
    k_scatter<<<eb_blocks, 256, 0, stream>>>(ei, eattr, rs, rank_, epack, E);

    hipMemsetAsync(pooled, 0, NGRAPH * HDIM * sizeof(float), stream);
    k_encode<<<2048, 256, 0, stream>>>(x, enc_w, enc_b, hb, hq, N);

    int gblocks = (N + 127) / 128;
    int ablocks = (N * 64 + 255) / 256;

    // layer 0
    k_agg<<<ablocks, 256, 0, stream>>>(hq, hb, rs, epack, eenc_w, eenc_b, eps + 0, zb, N);
    k_gemm<0,0><<<gblocks, 256, 0, stream>>>(zb, w1, b1, nullptr, nullptr, zb, nullptr, N);
    k_gemm<1,1><<<gblocks, 256, 0, stream>>>(zb, w2, b2, gamma, beta, hb, hq, N);
    // layer 1
    k_agg<<<ablocks, 256, 0, stream>>>(hq, hb, rs, epack, eenc_w, eenc_b, eps + 1, zb, N);
    k_gemm<0,0><<<gblocks, 256, 0, stream>>>(zb, w1 + (size_t)HDIM * HDIM, b1 + HDIM,
                                             nullptr, nullptr, zb, nullptr, N);
    k_gemm<1,0><<<gblocks, 256, 0, stream>>>(zb, w2 + (size_t)HDIM * HDIM, b2 + HDIM,
                                             gamma + HDIM, beta + HDIM, hb, nullptr, N);

    k_pool2<<<(N + PCHUNK - 1) / PCHUNK, 256, 0, stream>>>(hb, batch, pooled, N);
    k_classify<<<NGRAPH, 64, 0, stream>>>(pooled, batch, cw1, cb1, cw2, cb2, (float*)d_out, N);
}

// Round 8
// 424.072 us; speedup vs baseline: 1.0639x; 1.0639x over previous
//
#include <hip/hip_runtime.h>

#define HDIM 128
#define NGRAPH 64
#define INVSTD 0.99999500003749972f   // 1/sqrt(1+1e-5)

typedef unsigned short ushort_t;
typedef unsigned int uint_t;
typedef __attribute__((ext_vector_type(8))) short bf16x8;   // 8 bf16 = 4 VGPR
typedef __attribute__((ext_vector_type(4))) float f32x4;

__device__ __forceinline__ float bf2f(uint_t u) {            // low 16 bits
    return __int_as_float((int)(u << 16));
}
__device__ __forceinline__ float bf2f_hi(uint_t u) {
    return __int_as_float((int)(u & 0xFFFF0000u));
}
__device__ __forceinline__ uint_t f2bf(float f) {            // RNE
    uint_t x = __float_as_uint(f);
    return (x + 0x7FFFu + ((x >> 16) & 1u)) >> 16;
}
__device__ __forceinline__ uint_t pack2(float a, float b) {
    return f2bf(a) | (f2bf(b) << 16);
}

// ---------------- encode: hb[n][k] = bf16(x[n]*ew[k] + eb[k]) ----------------
__global__ void k_encode(const float* __restrict__ x, const float* __restrict__ ew,
                         const float* __restrict__ eb, ushort_t* __restrict__ hb, int N) {
    int tid = blockIdx.x * blockDim.x + threadIdx.x;
    int stride = gridDim.x * blockDim.x;
    int q = tid & 15;
    float4 wa = ((const float4*)ew)[2 * q];
    float4 wb = ((const float4*)ew)[2 * q + 1];
    float4 ba = ((const float4*)eb)[2 * q];
    float4 bb = ((const float4*)eb)[2 * q + 1];
    int total = N * 16;
    for (int t = tid; t < total; t += stride) {
        int n = t >> 4;
        float xv = x[n];
        uint4 o;
        o.x = pack2(fmaf(xv, wa.x, ba.x), fmaf(xv, wa.y, ba.y));
        o.y = pack2(fmaf(xv, wa.z, ba.z), fmaf(xv, wa.w, ba.w));
        o.z = pack2(fmaf(xv, wb.x, bb.x), fmaf(xv, wb.y, bb.y));
        o.w = pack2(fmaf(xv, wb.z, bb.z), fmaf(xv, wb.w, bb.w));
        ((uint4*)(hb + (size_t)n * HDIM))[q] = o;
    }
}

// ---------------- CSR build ----------------
__global__ void k_hist(const int* __restrict__ ei, int* deg, int* __restrict__ rank_, int E) {
    int e = blockIdx.x * 256 + threadIdx.x;
    if (e < E) {
        int d = ei[E + e];
        rank_[e] = atomicAdd(&deg[d], 1);
    }
}

__global__ void k_scan1(const int* __restrict__ deg, int* rs, int* bsum, int N) {
    __shared__ int sm[256];
    int gid = blockIdx.x * 256 + threadIdx.x;
    int v = (gid < N) ? deg[gid] : 0;
    sm[threadIdx.x] = v;
    __syncthreads();
    #pragma unroll
    for (int off = 1; off < 256; off <<= 1) {
        int t = (threadIdx.x >= off) ? sm[threadIdx.x - off] : 0;
        __syncthreads();
        sm[threadIdx.x] += t;
        __syncthreads();
    }
    if (gid < N) rs[gid] = sm[threadIdx.x] - v;
    if (threadIdx.x == 255) bsum[blockIdx.x] = sm[255];
}

__global__ void k_scan2(int* bsum, int nb) {
    __shared__ int sm[512];
    int t = threadIdx.x;
    int v = (t < nb) ? bsum[t] : 0;
    sm[t] = v;
    __syncthreads();
    #pragma unroll
    for (int off = 1; off < 512; off <<= 1) {
        int u = (t >= off) ? sm[t - off] : 0;
        __syncthreads();
        sm[t] += u;
        __syncthreads();
    }
    if (t < nb) bsum[t] = sm[t] - v;
}

__global__ void k_scan3(int* rs, const int* __restrict__ bsum, int N, int E) {
    int gid = blockIdx.x * 256 + threadIdx.x;
    if (gid < N) rs[gid] += bsum[gid >> 8];
    if (gid == N) rs[N] = E;
}

__global__ void k_scatter(const int* __restrict__ ei, const float* __restrict__ attr,
                          const int* __restrict__ rs, const int* __restrict__ rank_,
                          int2* __restrict__ epack, int E) {
    int e = blockIdx.x * 256 + threadIdx.x;
    if (e < E) {
        int s = ei[e], d = ei[E + e];
        int p = rs[d] + rank_[e];
        epack[p] = make_int2(s, __float_as_int(attr[e]));
    }
}

// ------- aggregation (round-6 winner): 16 lanes/edge, uint4 bf16 gathers -------
__device__ __forceinline__ void acc_edge(float acc[8], const uint4& u, float at,
        const float4& wa, const float4& wb, const float4& ba, const float4& bb) {
    acc[0] += fmaxf(bf2f(u.x & 0xFFFFu) + fmaf(at, wa.x, ba.x), 0.f);
    acc[1] += fmaxf(bf2f(u.x >> 16)     + fmaf(at, wa.y, ba.y), 0.f);
    acc[2] += fmaxf(bf2f(u.y & 0xFFFFu) + fmaf(at, wa.z, ba.z), 0.f);
    acc[3] += fmaxf(bf2f(u.y >> 16)     + fmaf(at, wa.w, ba.w), 0.f);
    acc[4] += fmaxf(bf2f(u.z & 0xFFFFu) + fmaf(at, wb.x, bb.x), 0.f);
    acc[5] += fmaxf(bf2f(u.z >> 16)     + fmaf(at, wb.y, bb.y), 0.f);
    acc[6] += fmaxf(bf2f(u.w & 0xFFFFu) + fmaf(at, wb.z, bb.z), 0.f);
    acc[7] += fmaxf(bf2f(u.w >> 16)     + fmaf(at, wb.w, bb.w), 0.f);
}

__global__ __launch_bounds__(256) void k_agg(
    const ushort_t* __restrict__ hb, const int* __restrict__ rs,
    const int2* __restrict__ epack,
    const float* __restrict__ ew, const float* __restrict__ eb,
    const float* __restrict__ epsp, ushort_t* __restrict__ zb, int N) {
    int wave = (blockIdx.x * 256 + threadIdx.x) >> 6;
    if (wave >= N) return;
    int lane = threadIdx.x & 63;
    int p = lane >> 4;          // quarter-wave: edges j ≡ p (mod 4)
    int q = lane & 15;          // features 8q..8q+7
    int n = wave;
    int beg = rs[n];
    int cntE = rs[n + 1] - beg;
    float4 wa = ((const float4*)ew)[2 * q], wb = ((const float4*)ew)[2 * q + 1];
    float4 ba = ((const float4*)eb)[2 * q], bb = ((const float4*)eb)[2 * q + 1];

    float acc[8] = {0.f, 0.f, 0.f, 0.f, 0.f, 0.f, 0.f, 0.f};
    float acc2[8] = {0.f, 0.f, 0.f, 0.f, 0.f, 0.f, 0.f, 0.f};
    int j = p;
    for (; j + 4 < cntE; j += 8) {
        int2 e1 = epack[beg + j];
        int2 e2 = epack[beg + j + 4];
        uint4 u1 = *(const uint4*)(hb + (size_t)e1.x * HDIM + q * 8);
        uint4 u2 = *(const uint4*)(hb + (size_t)e2.x * HDIM + q * 8);
        acc_edge(acc,  u1, __int_as_float(e1.y), wa, wb, ba, bb);
        acc_edge(acc2, u2, __int_as_float(e2.y), wa, wb, ba, bb);
    }
    if (j < cntE) {
        int2 e1 = epack[beg + j];
        uint4 u1 = *(const uint4*)(hb + (size_t)e1.x * HDIM + q * 8);
        acc_edge(acc, u1, __int_as_float(e1.y), wa, wb, ba, bb);
    }
    #pragma unroll
    for (int k = 0; k < 8; ++k) {
        float v = acc[k] + acc2[k];
        v += __shfl_xor(v, 16);
        v += __shfl_xor(v, 32);
        acc[k] = v;
    }
    if (p == 0) {
        float sc = 1.f + epsp[0];
        uint4 u = *(const uint4*)(hb + (size_t)n * HDIM + q * 8);
        uint4 ob;
        ob.x = pack2(fmaf(sc, bf2f(u.x & 0xFFFFu), acc[0]),
                     fmaf(sc, bf2f(u.x >> 16),     acc[1]));
        ob.y = pack2(fmaf(sc, bf2f(u.y & 0xFFFFu), acc[2]),
                     fmaf(sc, bf2f(u.y >> 16),     acc[3]));
        ob.z = pack2(fmaf(sc, bf2f(u.z & 0xFFFFu), acc[4]),
                     fmaf(sc, bf2f(u.z >> 16),     acc[5]));
        ob.w = pack2(fmaf(sc, bf2f(u.w & 0xFFFFu), acc[6]),
                     fmaf(sc, bf2f(u.w >> 16),     acc[7]));
        *(uint4*)(zb + (size_t)n * HDIM + q * 8) = ob;
    }
}

// ------------- MFMA GEMM: out = epilogue(A @ W + bias), all [*,128] -------------
// MODE 0: relu -> out.  MODE 1: BN+relu -> out.
// POOL 1 (implies MODE 1): no out store; accumulate into pooled[batch[row]] via
//   LDS window (batch is sorted, block = 128 contiguous rows).
#define WTPAD 136
#define PW 4
template<int MODE, int POOL>
__global__ __launch_bounds__(256) void k_gemm(
    const ushort_t* __restrict__ A, const float* __restrict__ W,
    const float* __restrict__ bias, const float* __restrict__ gam,
    const float* __restrict__ bet, ushort_t* __restrict__ out,
    const int* __restrict__ batch, float* __restrict__ pooled, int N) {
    __shared__ ushort_t wt[128 * WTPAD];        // wt[n][k] = bf16(W[k][n])
    __shared__ float pacc[POOL ? PW : 1][POOL ? HDIM : 1];
    int tid = threadIdx.x;
    #pragma unroll
    for (int i = 0; i < 64; ++i) {
        int idx = i * 256 + tid;
        int k = idx >> 7, n = idx & 127;
        wt[n * WTPAD + k] = (ushort_t)f2bf(W[idx]);
    }
    if (POOL) {
        #pragma unroll
        for (int i = tid; i < PW * HDIM; i += 256) ((float*)pacc)[i] = 0.f;
    }
    __syncthreads();

    int wid = tid >> 6, lane = tid & 63;
    int ra = lane & 15, qa = lane >> 4;
    int g0 = 0;
    if (POOL) g0 = batch[blockIdx.x * 128];     // block's first (sorted) graph

    bf16x8 bfr[4][8];
    #pragma unroll
    for (int ks = 0; ks < 4; ++ks)
        #pragma unroll
        for (int nf = 0; nf < 8; ++nf)
            bfr[ks][nf] = *(const bf16x8*)&wt[(nf * 16 + ra) * WTPAD + ks * 32 + qa * 8];

    float bi[8], gg[8], be[8];
    #pragma unroll
    for (int nf = 0; nf < 8; ++nf) {
        int col = nf * 16 + ra;
        bi[nf] = bias[col];
        if (MODE == 1) { gg[nf] = gam[col]; be[nf] = bet[col]; }
    }

    bf16x8 azero;
    #pragma unroll
    for (int j = 0; j < 8; ++j) azero[j] = 0;

    #pragma unroll
    for (int it = 0; it < 2; ++it) {
        int m0 = blockIdx.x * 128 + it * 64 + wid * 16;
        int mr = m0 + ra;
        bf16x8 afr[4];
        #pragma unroll
        for (int ks = 0; ks < 4; ++ks)
            afr[ks] = (mr < N) ? *(const bf16x8*)&A[(size_t)mr * HDIM + ks * 32 + qa * 8]
                               : azero;
        f32x4 acc[8];
        #pragma unroll
        for (int nf = 0; nf < 8; ++nf)
            #pragma unroll
            for (int j = 0; j < 4; ++j) acc[nf][j] = 0.f;
        #pragma unroll
        for (int ks = 0; ks < 4; ++ks)
            #pragma unroll
            for (int nf = 0; nf < 8; ++nf)
                acc[nf] = __builtin_amdgcn_mfma_f32_16x16x32_bf16(afr[ks], bfr[ks][nf], acc[nf], 0, 0, 0);
        #pragma unroll
        for (int r = 0; r < 4; ++r) {
            int row = m0 + qa * 4 + r;
            if (row < N) {
                int w = 0;
                if (POOL) w = batch[row] - g0;
                #pragma unroll
                for (int nf = 0; nf < 8; ++nf) {
                    float v = acc[nf][r] + bi[nf];
                    if (MODE == 0) v = fmaxf(v, 0.f);
                    else           v = fmaxf(fmaf(gg[nf] * v, INVSTD, be[nf]), 0.f);
                    int col = nf * 16 + ra;
                    if (POOL) {
                        if (w < PW) atomicAdd(&pacc[w][col], v);
                        else        atomicAdd(&pooled[(size_t)(g0 + w) * HDIM + col], v);
                    } else {
                        out[(size_t)row * HDIM + col] = (ushort_t)f2bf(v);
                    }
                }
            }
        }
    }
    if (POOL) {
        __syncthreads();
        for (int i = tid; i < PW * HDIM; i += 256) {
            int w = i >> 7, f = i & 127;
            float v = pacc[w][f];
            if (v != 0.f) atomicAdd(&pooled[(size_t)(g0 + w) * HDIM + f], v);
        }
    }
}

// ------------- classifier (count fused via binary search) -------------
__global__ void k_classify(const float* __restrict__ pooled, const int* __restrict__ batch,
                           const float* __restrict__ cw1, const float* __restrict__ cb1,
                           const float* __restrict__ cw2, const float* __restrict__ cb2,
                           float* __restrict__ out, int N) {
    __shared__ float p[HDIM];
    int g = blockIdx.x, j = threadIdx.x;
    int lo = 0, hi = N;
    while (lo < hi) { int m = (lo + hi) >> 1; if (batch[m] < g) lo = m + 1; else hi = m; }
    int lo2 = lo, hi2 = N;
    while (lo2 < hi2) { int m = (lo2 + hi2) >> 1; if (batch[m] < g + 1) lo2 = m + 1; else hi2 = m; }
    float c = fmaxf((float)(lo2 - lo), 1.f);
    p[j]      = pooled[g * HDIM + j] / c;
    p[j + 64] = pooled[g * HDIM + j + 64] / c;
    __syncthreads();
    float acc = cb1[j];
    #pragma unroll 4
    for (int k = 0; k < HDIM; ++k) acc = fmaf(p[k], cw1[k * 64 + j], acc);
    acc = fmaxf(acc, 0.f);
    float v = acc * cw2[j];
    #pragma unroll
    for (int off = 32; off > 0; off >>= 1) v += __shfl_down(v, off, 64);
    if (j == 0) out[g] = 1.f / (1.f + expf(-(v + cb2[0])));
}

static inline size_t align_up(size_t v, size_t a) { return (v + a - 1) & ~(a - 1); }

extern "C" void kernel_launch(void* const* d_in, const int* in_sizes, int n_in,
                              void* d_out, int out_size, void* d_ws, size_t ws_size,
                              hipStream_t stream) {
    const float* x      = (const float*)d_in[0];
    const int*   ei     = (const int*)d_in[1];
    const float* eattr  = (const float*)d_in[2];
    const int*   batch  = (const int*)d_in[3];
    const float* enc_w  = (const float*)d_in[4];
    const float* enc_b  = (const float*)d_in[5];
    const float* eenc_w = (const float*)d_in[6];
    const float* eenc_b = (const float*)d_in[7];
    const float* eps    = (const float*)d_in[8];
    const float* w1     = (const float*)d_in[9];
    const float* b1     = (const float*)d_in[10];
    const float* w2     = (const float*)d_in[11];
    const float* b2     = (const float*)d_in[12];
    const float* gamma  = (const float*)d_in[13];
    const float* beta   = (const float*)d_in[14];
    const float* cw1    = (const float*)d_in[15];
    const float* cb1    = (const float*)d_in[16];
    const float* cw2    = (const float*)d_in[17];
    const float* cb2    = (const float*)d_in[18];

    int N = in_sizes[0];          // 100000
    int E = in_sizes[2];          // 1600000

    char* wsb = (char*)d_ws;
    size_t off = 0;
    ushort_t* hb  = (ushort_t*)(wsb + off); off = align_up(off + (size_t)N * HDIM * 2, 256);
    ushort_t* zb  = (ushort_t*)(wsb + off); off = align_up(off + (size_t)N * HDIM * 2, 256);
    float* pooled = (float*)(wsb + off);    off = align_up(off + NGRAPH * HDIM * 4, 256);
    int*   deg    = (int*)(wsb + off);      off = align_up(off + (size_t)N * 4, 256);
    int*   rs     = (int*)(wsb + off);      off = align_up(off + (size_t)(N + 1) * 4, 256);
    int*   rank_  = (int*)(wsb + off);      off = align_up(off + (size_t)E * 4, 256);
    int*   bsum   = (int*)(wsb + off);      off = align_up(off + 2048 * 4, 256);
    int2*  epack  = (int2*)(wsb + off);     off = align_up(off + (size_t)E * 8, 256);

    int nb = (N + 255) / 256;
    int eb_blocks = (E + 255) / 256;

    // CSR build
    hipMemsetAsync(deg, 0, (size_t)N * 4, stream);
    k_hist<<<eb_blocks, 256, 0, stream>>>(ei, deg, rank_, E);
    k_scan1<<<nb, 256, 0, stream>>>(deg, rs, bsum, N);
    k_scan2<<<1, 512, 0, stream>>>(bsum, nb);
    k_scan3<<<(N + 256) / 256, 256, 0, stream>>>(rs, bsum, N, E);
    k_scatter<<<eb_blocks, 256, 0, stream>>>(ei, eattr, rs, rank_, epack, E);

    hipMemsetAsync(pooled, 0, NGRAPH * HDIM * sizeof(float), stream);
    k_encode<<<2048, 256, 0, stream>>>(x, enc_w, enc_b, hb, N);

    int gblocks = (N + 127) / 128;
    int ablocks = (N * 64 + 255) / 256;

    // layer 0
    k_agg<<<ablocks, 256, 0, stream>>>(hb, rs, epack, eenc_w, eenc_b, eps + 0, zb, N);
    k_gemm<0,0><<<gblocks, 256, 0, stream>>>(zb, w1, b1, nullptr, nullptr, zb, nullptr, nullptr, N);
    k_gemm<1,0><<<gblocks, 256, 0, stream>>>(zb, w2, b2, gamma, beta, hb, nullptr, nullptr, N);
    // layer 1
    k_agg<<<ablocks, 256, 0, stream>>>(hb, rs, epack, eenc_w, eenc_b, eps + 1, zb, N);
    k_gemm<0,0><<<gblocks, 256, 0, stream>>>(zb, w1 + (size_t)HDIM * HDIM, b1 + HDIM,
                                             nullptr, nullptr, zb, nullptr, nullptr, N);
    // final GEMM: BN+relu fused with global mean-pool accumulation (no h store)
    k_gemm<1,1><<<gblocks, 256, 0, stream>>>(zb, w2 + (size_t)HDIM * HDIM, b2 + HDIM,
                                             gamma + HDIM, beta + HDIM, nullptr, batch, pooled, N);

    k_classify<<<NGRAPH, 64, 0, stream>>>(pooled, batch, cw1, cb1, cw2, cb2, (float*)d_out, N);
}

// Round 9
// 374.387 us; speedup vs baseline: 1.2051x; 1.1327x over previous
//
#include <hip/hip_runtime.h>

#define HDIM 128
#define NGRAPH 64
#define INVSTD 0.99999500003749972f   // 1/sqrt(1+1e-5)

typedef unsigned short ushort_t;
typedef unsigned int uint_t;
typedef __attribute__((ext_vector_type(8))) short bf16x8;   // 8 bf16 = 4 VGPR
typedef __attribute__((ext_vector_type(4))) float f32x4;

__device__ __forceinline__ float bf2f(uint_t u) {            // low 16 bits
    return __int_as_float((int)(u << 16));
}
__device__ __forceinline__ float bf2f_hi(uint_t u) {
    return __int_as_float((int)(u & 0xFFFF0000u));
}
__device__ __forceinline__ uint_t f2bf(float f) {            // RNE
    uint_t x = __float_as_uint(f);
    return (x + 0x7FFFu + ((x >> 16) & 1u)) >> 16;
}
__device__ __forceinline__ uint_t pack2(float a, float b) {
    return f2bf(a) | (f2bf(b) << 16);
}

// ---------------- encode: hb[n][k] = bf16(x[n]*ew[k] + eb[k]) ----------------
__global__ void k_encode(const float* __restrict__ x, const float* __restrict__ ew,
                         const float* __restrict__ eb, ushort_t* __restrict__ hb, int N) {
    int tid = blockIdx.x * blockDim.x + threadIdx.x;
    int stride = gridDim.x * blockDim.x;
    int q = tid & 15;
    float4 wa = ((const float4*)ew)[2 * q];
    float4 wb = ((const float4*)ew)[2 * q + 1];
    float4 ba = ((const float4*)eb)[2 * q];
    float4 bb = ((const float4*)eb)[2 * q + 1];
    int total = N * 16;
    for (int t = tid; t < total; t += stride) {
        int n = t >> 4;
        float xv = x[n];
        uint4 o;
        o.x = pack2(fmaf(xv, wa.x, ba.x), fmaf(xv, wa.y, ba.y));
        o.y = pack2(fmaf(xv, wa.z, ba.z), fmaf(xv, wa.w, ba.w));
        o.z = pack2(fmaf(xv, wb.x, bb.x), fmaf(xv, wb.y, bb.y));
        o.w = pack2(fmaf(xv, wb.z, bb.z), fmaf(xv, wb.w, bb.w));
        ((uint4*)(hb + (size_t)n * HDIM))[q] = o;
    }
}

// ---------------- CSR build ----------------
__global__ void k_hist(const int* __restrict__ ei, int* deg, int* __restrict__ rank_, int E) {
    int e = blockIdx.x * 256 + threadIdx.x;
    if (e < E) {
        int d = ei[E + e];
        rank_[e] = atomicAdd(&deg[d], 1);
    }
}

__global__ void k_scan1(const int* __restrict__ deg, int* rs, int* bsum, int N) {
    __shared__ int sm[256];
    int gid = blockIdx.x * 256 + threadIdx.x;
    int v = (gid < N) ? deg[gid] : 0;
    sm[threadIdx.x] = v;
    __syncthreads();
    #pragma unroll
    for (int off = 1; off < 256; off <<= 1) {
        int t = (threadIdx.x >= off) ? sm[threadIdx.x - off] : 0;
        __syncthreads();
        sm[threadIdx.x] += t;
        __syncthreads();
    }
    if (gid < N) rs[gid] = sm[threadIdx.x] - v;
    if (threadIdx.x == 255) bsum[blockIdx.x] = sm[255];
}

__global__ void k_scan2(int* bsum, int nb) {
    __shared__ int sm[512];
    int t = threadIdx.x;
    int v = (t < nb) ? bsum[t] : 0;
    sm[t] = v;
    __syncthreads();
    #pragma unroll
    for (int off = 1; off < 512; off <<= 1) {
        int u = (t >= off) ? sm[t - off] : 0;
        __syncthreads();
        sm[t] += u;
        __syncthreads();
    }
    if (t < nb) bsum[t] = sm[t] - v;
}

__global__ void k_scan3(int* rs, const int* __restrict__ bsum, int N, int E) {
    int gid = blockIdx.x * 256 + threadIdx.x;
    if (gid < N) rs[gid] += bsum[gid >> 8];
    if (gid == N) rs[N] = E;
}

__global__ void k_scatter(const int* __restrict__ ei, const float* __restrict__ attr,
                          const int* __restrict__ rs, const int* __restrict__ rank_,
                          int2* __restrict__ epack, int E) {
    int e = blockIdx.x * 256 + threadIdx.x;
    if (e < E) {
        int s = ei[e], d = ei[E + e];
        int p = rs[d] + rank_[e];
        epack[p] = make_int2(s, __float_as_int(attr[e]));
    }
}

// ------- aggregation (round-6 winner): 16 lanes/edge, uint4 bf16 gathers -------
__device__ __forceinline__ void acc_edge(float acc[8], const uint4& u, float at,
        const float4& wa, const float4& wb, const float4& ba, const float4& bb) {
    acc[0] += fmaxf(bf2f(u.x & 0xFFFFu) + fmaf(at, wa.x, ba.x), 0.f);
    acc[1] += fmaxf(bf2f(u.x >> 16)     + fmaf(at, wa.y, ba.y), 0.f);
    acc[2] += fmaxf(bf2f(u.y & 0xFFFFu) + fmaf(at, wa.z, ba.z), 0.f);
    acc[3] += fmaxf(bf2f(u.y >> 16)     + fmaf(at, wa.w, ba.w), 0.f);
    acc[4] += fmaxf(bf2f(u.z & 0xFFFFu) + fmaf(at, wb.x, bb.x), 0.f);
    acc[5] += fmaxf(bf2f(u.z >> 16)     + fmaf(at, wb.y, bb.y), 0.f);
    acc[6] += fmaxf(bf2f(u.w & 0xFFFFu) + fmaf(at, wb.z, bb.z), 0.f);
    acc[7] += fmaxf(bf2f(u.w >> 16)     + fmaf(at, wb.w, bb.w), 0.f);
}

__global__ __launch_bounds__(256) void k_agg(
    const ushort_t* __restrict__ hb, const int* __restrict__ rs,
    const int2* __restrict__ epack,
    const float* __restrict__ ew, const float* __restrict__ eb,
    const float* __restrict__ epsp, ushort_t* __restrict__ zb, int N) {
    int wave = (blockIdx.x * 256 + threadIdx.x) >> 6;
    if (wave >= N) return;
    int lane = threadIdx.x & 63;
    int p = lane >> 4;          // quarter-wave: edges j ≡ p (mod 4)
    int q = lane & 15;          // features 8q..8q+7
    int n = wave;
    int beg = rs[n];
    int cntE = rs[n + 1] - beg;
    float4 wa = ((const float4*)ew)[2 * q], wb = ((const float4*)ew)[2 * q + 1];
    float4 ba = ((const float4*)eb)[2 * q], bb = ((const float4*)eb)[2 * q + 1];

    float acc[8] = {0.f, 0.f, 0.f, 0.f, 0.f, 0.f, 0.f, 0.f};
    float acc2[8] = {0.f, 0.f, 0.f, 0.f, 0.f, 0.f, 0.f, 0.f};
    int j = p;
    for (; j + 4 < cntE; j += 8) {
        int2 e1 = epack[beg + j];
        int2 e2 = epack[beg + j + 4];
        uint4 u1 = *(const uint4*)(hb + (size_t)e1.x * HDIM + q * 8);
        uint4 u2 = *(const uint4*)(hb + (size_t)e2.x * HDIM + q * 8);
        acc_edge(acc,  u1, __int_as_float(e1.y), wa, wb, ba, bb);
        acc_edge(acc2, u2, __int_as_float(e2.y), wa, wb, ba, bb);
    }
    if (j < cntE) {
        int2 e1 = epack[beg + j];
        uint4 u1 = *(const uint4*)(hb + (size_t)e1.x * HDIM + q * 8);
        acc_edge(acc, u1, __int_as_float(e1.y), wa, wb, ba, bb);
    }
    #pragma unroll
    for (int k = 0; k < 8; ++k) {
        float v = acc[k] + acc2[k];
        v += __shfl_xor(v, 16);
        v += __shfl_xor(v, 32);
        acc[k] = v;
    }
    if (p == 0) {
        float sc = 1.f + epsp[0];
        uint4 u = *(const uint4*)(hb + (size_t)n * HDIM + q * 8);
        uint4 ob;
        ob.x = pack2(fmaf(sc, bf2f(u.x & 0xFFFFu), acc[0]),
                     fmaf(sc, bf2f(u.x >> 16),     acc[1]));
        ob.y = pack2(fmaf(sc, bf2f(u.y & 0xFFFFu), acc[2]),
                     fmaf(sc, bf2f(u.y >> 16),     acc[3]));
        ob.z = pack2(fmaf(sc, bf2f(u.z & 0xFFFFu), acc[4]),
                     fmaf(sc, bf2f(u.z >> 16),     acc[5]));
        ob.w = pack2(fmaf(sc, bf2f(u.w & 0xFFFFu), acc[6]),
                     fmaf(sc, bf2f(u.w >> 16),     acc[7]));
        *(uint4*)(zb + (size_t)n * HDIM + q * 8) = ob;
    }
}

// ------------- MFMA GEMM: out = epilogue(A @ W + bias), all [*,128] -------------
// MODE 0: relu -> out.  MODE 1: BN+relu -> out.
#define WTPAD 136
template<int MODE>
__global__ __launch_bounds__(256) void k_gemm(
    const ushort_t* __restrict__ A, const float* __restrict__ W,
    const float* __restrict__ bias, const float* __restrict__ gam,
    const float* __restrict__ bet, ushort_t* __restrict__ out, int N) {
    __shared__ ushort_t wt[128 * WTPAD];        // wt[n][k] = bf16(W[k][n])
    int tid = threadIdx.x;
    #pragma unroll
    for (int i = 0; i < 64; ++i) {
        int idx = i * 256 + tid;
        int k = idx >> 7, n = idx & 127;
        wt[n * WTPAD + k] = (ushort_t)f2bf(W[idx]);
    }
    __syncthreads();

    int wid = tid >> 6, lane = tid & 63;
    int ra = lane & 15, qa = lane >> 4;

    bf16x8 bfr[4][8];
    #pragma unroll
    for (int ks = 0; ks < 4; ++ks)
        #pragma unroll
        for (int nf = 0; nf < 8; ++nf)
            bfr[ks][nf] = *(const bf16x8*)&wt[(nf * 16 + ra) * WTPAD + ks * 32 + qa * 8];

    float bi[8], gg[8], be[8];
    #pragma unroll
    for (int nf = 0; nf < 8; ++nf) {
        int col = nf * 16 + ra;
        bi[nf] = bias[col];
        if (MODE == 1) { gg[nf] = gam[col]; be[nf] = bet[col]; }
    }

    bf16x8 azero;
    #pragma unroll
    for (int j = 0; j < 8; ++j) azero[j] = 0;

    #pragma unroll
    for (int it = 0; it < 2; ++it) {
        int m0 = blockIdx.x * 128 + it * 64 + wid * 16;
        int mr = m0 + ra;
        bf16x8 afr[4];
        #pragma unroll
        for (int ks = 0; ks < 4; ++ks)
            afr[ks] = (mr < N) ? *(const bf16x8*)&A[(size_t)mr * HDIM + ks * 32 + qa * 8]
                               : azero;
        f32x4 acc[8];
        #pragma unroll
        for (int nf = 0; nf < 8; ++nf)
            #pragma unroll
            for (int j = 0; j < 4; ++j) acc[nf][j] = 0.f;
        #pragma unroll
        for (int ks = 0; ks < 4; ++ks)
            #pragma unroll
            for (int nf = 0; nf < 8; ++nf)
                acc[nf] = __builtin_amdgcn_mfma_f32_16x16x32_bf16(afr[ks], bfr[ks][nf], acc[nf], 0, 0, 0);
        #pragma unroll
        for (int nf = 0; nf < 8; ++nf) {
            #pragma unroll
            for (int r = 0; r < 4; ++r) {
                int row = m0 + qa * 4 + r;
                if (row < N) {
                    float v = acc[nf][r] + bi[nf];
                    if (MODE == 0) v = fmaxf(v, 0.f);
                    else           v = fmaxf(fmaf(gg[nf] * v, INVSTD, be[nf]), 0.f);
                    out[(size_t)row * HDIM + nf * 16 + ra] = (ushort_t)f2bf(v);
                }
            }
        }
    }
}

// ------------- pooling: segmented reduction over sorted batch (bf16 in) -------------
#define PCHUNK 256
#define PWIN 4
__global__ __launch_bounds__(256) void k_pool2(const ushort_t* __restrict__ hb,
                                               const int* __restrict__ batch,
                                               float* pooled, int N) {
    __shared__ float acc[PWIN][HDIM];
    int n0 = blockIdx.x * PCHUNK;
    if (n0 >= N) return;
    int n1 = min(n0 + PCHUNK, N);
    int g0 = batch[n0];
    int g1 = batch[n1 - 1];
    for (int i = threadIdx.x; i < PWIN * HDIM; i += 256) ((float*)acc)[i] = 0.f;
    __syncthreads();

    int grp = threadIdx.x >> 5;
    int q = threadIdx.x & 31;
    float4 racc = make_float4(0.f, 0.f, 0.f, 0.f);
    int gcur = g0;
    for (int n = n0 + grp; n < n1; n += 8) {
        int g = batch[n];
        if (g != gcur) {
            int w = gcur - g0;
            float* p = (w < PWIN) ? &acc[w][q * 4] : (pooled + gcur * HDIM + q * 4);
            atomicAdd(p + 0, racc.x); atomicAdd(p + 1, racc.y);
            atomicAdd(p + 2, racc.z); atomicAdd(p + 3, racc.w);
            racc = make_float4(0.f, 0.f, 0.f, 0.f);
            gcur = g;
        }
        uint2 u = ((const uint2*)(hb + (size_t)n * HDIM))[q];
        racc.x += bf2f(u.x);
        racc.y += bf2f_hi(u.x);
        racc.z += bf2f(u.y);
        racc.w += bf2f_hi(u.y);
    }
    {
        int w = gcur - g0;
        float* p = (w < PWIN) ? &acc[w][q * 4] : (pooled + gcur * HDIM + q * 4);
        atomicAdd(p + 0, racc.x); atomicAdd(p + 1, racc.y);
        atomicAdd(p + 2, racc.z); atomicAdd(p + 3, racc.w);
    }
    __syncthreads();

    int span = min(g1 - g0 + 1, PWIN);
    for (int i = threadIdx.x; i < span * HDIM; i += 256) {
        int w = i >> 7, f = i & 127;
        float v = acc[w][f];
        if (v != 0.f) atomicAdd(pooled + (g0 + w) * HDIM + f, v);
    }
}

// ------------- classifier (count fused via binary search) -------------
__global__ void k_classify(const float* __restrict__ pooled, const int* __restrict__ batch,
                           const float* __restrict__ cw1, const float* __restrict__ cb1,
                           const float* __restrict__ cw2, const float* __restrict__ cb2,
                           float* __restrict__ out, int N) {
    __shared__ float p[HDIM];
    int g = blockIdx.x, j = threadIdx.x;
    int lo = 0, hi = N;
    while (lo < hi) { int m = (lo + hi) >> 1; if (batch[m] < g) lo = m + 1; else hi = m; }
    int lo2 = lo, hi2 = N;
    while (lo2 < hi2) { int m = (lo2 + hi2) >> 1; if (batch[m] < g + 1) lo2 = m + 1; else hi2 = m; }
    float c = fmaxf((float)(lo2 - lo), 1.f);
    p[j]      = pooled[g * HDIM + j] / c;
    p[j + 64] = pooled[g * HDIM + j + 64] / c;
    __syncthreads();
    float acc = cb1[j];
    #pragma unroll 4
    for (int k = 0; k < HDIM; ++k) acc = fmaf(p[k], cw1[k * 64 + j], acc);
    acc = fmaxf(acc, 0.f);
    float v = acc * cw2[j];
    #pragma unroll
    for (int off = 32; off > 0; off >>= 1) v += __shfl_down(v, off, 64);
    if (j == 0) out[g] = 1.f / (1.f + expf(-(v + cb2[0])));
}

static inline size_t align_up(size_t v, size_t a) { return (v + a - 1) & ~(a - 1); }

extern "C" void kernel_launch(void* const* d_in, const int* in_sizes, int n_in,
                              void* d_out, int out_size, void* d_ws, size_t ws_size,
                              hipStream_t stream) {
    const float* x      = (const float*)d_in[0];
    const int*   ei     = (const int*)d_in[1];
    const float* eattr  = (const float*)d_in[2];
    const int*   batch  = (const int*)d_in[3];
    const float* enc_w  = (const float*)d_in[4];
    const float* enc_b  = (const float*)d_in[5];
    const float* eenc_w = (const float*)d_in[6];
    const float* eenc_b = (const float*)d_in[7];
    const float* eps    = (const float*)d_in[8];
    const float* w1     = (const float*)d_in[9];
    const float* b1     = (const float*)d_in[10];
    const float* w2     = (const float*)d_in[11];
    const float* b2     = (const float*)d_in[12];
    const float* gamma  = (const float*)d_in[13];
    const float* beta   = (const float*)d_in[14];
    const float* cw1    = (const float*)d_in[15];
    const float* cb1    = (const float*)d_in[16];
    const float* cw2    = (const float*)d_in[17];
    const float* cb2    = (const float*)d_in[18];

    int N = in_sizes[0];          // 100000
    int E = in_sizes[2];          // 1600000

    char* wsb = (char*)d_ws;
    size_t off = 0;
    ushort_t* hb  = (ushort_t*)(wsb + off); off = align_up(off + (size_t)N * HDIM * 2, 256);
    ushort_t* zb  = (ushort_t*)(wsb + off); off = align_up(off + (size_t)N * HDIM * 2, 256);
    float* pooled = (float*)(wsb + off);    off = align_up(off + NGRAPH * HDIM * 4, 256);
    int*   deg    = (int*)(wsb + off);      off = align_up(off + (size_t)N * 4, 256);
    int*   rs     = (int*)(wsb + off);      off = align_up(off + (size_t)(N + 1) * 4, 256);
    int*   rank_  = (int*)(wsb + off);      off = align_up(off + (size_t)E * 4, 256);
    int*   bsum   = (int*)(wsb + off);      off = align_up(off + 2048 * 4, 256);
    int2*  epack  = (int2*)(wsb + off);     off = align_up(off + (size_t)E * 8, 256);

    int nb = (N + 255) / 256;
    int eb_blocks = (E + 255) / 256;

    // CSR build
    hipMemsetAsync(deg, 0, (size_t)N * 4, stream);
    k_hist<<<eb_blocks, 256, 0, stream>>>(ei, deg, rank_, E);
    k_scan1<<<nb, 256, 0, stream>>>(deg, rs, bsum, N);
    k_scan2<<<1, 512, 0, stream>>>(bsum, nb);
    k_scan3<<<(N + 256) / 256, 256, 0, stream>>>(rs, bsum, N, E);
    k_scatter<<<eb_blocks, 256, 0, stream>>>(ei, eattr, rs, rank_, epack, E);

    hipMemsetAsync(pooled, 0, NGRAPH * HDIM * sizeof(float), stream);
    k_encode<<<2048, 256, 0, stream>>>(x, enc_w, enc_b, hb, N);

    int gblocks = (N + 127) / 128;
    int ablocks = (N * 64 + 255) / 256;

    // layer 0
    k_agg<<<ablocks, 256, 0, stream>>>(hb, rs, epack, eenc_w, eenc_b, eps + 0, zb, N);
    k_gemm<0><<<gblocks, 256, 0, stream>>>(zb, w1, b1, nullptr, nullptr, zb, N);
    k_gemm<1><<<gblocks, 256, 0, stream>>>(zb, w2, b2, gamma, beta, hb, N);
    // layer 1
    k_agg<<<ablocks, 256, 0, stream>>>(hb, rs, epack, eenc_w, eenc_b, eps + 1, zb, N);
    k_gemm<0><<<gblocks, 256, 0, stream>>>(zb, w1 + (size_t)HDIM * HDIM, b1 + HDIM,
                                           nullptr, nullptr, zb, N);
    k_gemm<1><<<gblocks, 256, 0, stream>>>(zb, w2 + (size_t)HDIM * HDIM, b2 + HDIM,
                                           gamma + HDIM, beta + HDIM, hb, N);

    k_pool2<<<(N + PCHUNK - 1) / PCHUNK, 256, 0, stream>>>(hb, batch, pooled, N);
    k_classify<<<NGRAPH, 64, 0, stream>>>(pooled, batch, cw1, cb1, cw2, cb2, (float*)d_out, N);
}

// Round 10
// 341.316 us; speedup vs baseline: 1.3219x; 1.0969x over previous
//
#include <hip/hip_runtime.h>

#define HDIM 128
#define NGRAPH 64
#define INVSTD 0.99999500003749972f   // 1/sqrt(1+1e-5)
#define WTPAD 136
#define WSLOT (128 * WTPAD)

typedef unsigned short ushort_t;
typedef unsigned int uint_t;
typedef __attribute__((ext_vector_type(8))) short bf16x8;   // 8 bf16 = 4 VGPR
typedef __attribute__((ext_vector_type(4))) float f32x4;

__device__ __forceinline__ float bf2f(uint_t u) {            // low 16 bits
    return __int_as_float((int)(u << 16));
}
__device__ __forceinline__ float bf2f_hi(uint_t u) {
    return __int_as_float((int)(u & 0xFFFF0000u));
}
__device__ __forceinline__ uint_t f2bf(float f) {            // RNE
    uint_t x = __float_as_uint(f);
    return (x + 0x7FFFu + ((x >> 16) & 1u)) >> 16;
}
__device__ __forceinline__ uint_t pack2(float a, float b) {
    return f2bf(a) | (f2bf(b) << 16);
}

// ---- encode: hb[n][k] = bf16(x[n]*ew[k] + enc_b[k] + eenc_b[k])  (eb-folded table)
__global__ void k_encode(const float* __restrict__ x, const float* __restrict__ ew,
                         const float* __restrict__ enb, const float* __restrict__ ebe,
                         ushort_t* __restrict__ hb, int N) {
    int tid = blockIdx.x * blockDim.x + threadIdx.x;
    int stride = gridDim.x * blockDim.x;
    int q = tid & 15;
    float4 wa = ((const float4*)ew)[2 * q];
    float4 wb = ((const float4*)ew)[2 * q + 1];
    float4 ba = ((const float4*)enb)[2 * q];
    float4 bb = ((const float4*)enb)[2 * q + 1];
    float4 ea = ((const float4*)ebe)[2 * q];
    float4 eb2 = ((const float4*)ebe)[2 * q + 1];
    ba.x += ea.x; ba.y += ea.y; ba.z += ea.z; ba.w += ea.w;
    bb.x += eb2.x; bb.y += eb2.y; bb.z += eb2.z; bb.w += eb2.w;
    int total = N * 16;
    for (int t = tid; t < total; t += stride) {
        int n = t >> 4;
        float xv = x[n];
        uint4 o;
        o.x = pack2(fmaf(xv, wa.x, ba.x), fmaf(xv, wa.y, ba.y));
        o.y = pack2(fmaf(xv, wa.z, ba.z), fmaf(xv, wa.w, ba.w));
        o.z = pack2(fmaf(xv, wb.x, bb.x), fmaf(xv, wb.y, bb.y));
        o.w = pack2(fmaf(xv, wb.z, bb.z), fmaf(xv, wb.w, bb.w));
        ((uint4*)(hb + (size_t)n * HDIM))[q] = o;
    }
}

// ---- weight prep: wtg[slot][n*WTPAD+k] = bf16(W_slot[k][n]); slots {w1_0,w2_0,w1_1,w2_1}
__global__ void k_prepw(const float* __restrict__ w1, const float* __restrict__ w2,
                        ushort_t* __restrict__ wtg) {
    int t = blockIdx.x * 256 + threadIdx.x;
    if (t >= 4 * 16384) return;
    int w = t >> 14, idx = t & 16383;
    int k = idx >> 7, n = idx & 127;
    const float* src = ((w & 1) ? w2 : w1) + (size_t)(w >> 1) * 16384;
    wtg[(size_t)w * WSLOT + n * WTPAD + k] = (ushort_t)f2bf(src[idx]);
}

// ---------------- CSR build ----------------
__global__ void k_hist(const int* __restrict__ ei, int* deg, int* __restrict__ rank_, int E) {
    int e = blockIdx.x * 256 + threadIdx.x;
    if (e < E) {
        int d = ei[E + e];
        rank_[e] = atomicAdd(&deg[d], 1);
    }
}

__global__ void k_scan1(const int* __restrict__ deg, int* rs, int* bsum, int N) {
    __shared__ int sm[256];
    int gid = blockIdx.x * 256 + threadIdx.x;
    int v = (gid < N) ? deg[gid] : 0;
    sm[threadIdx.x] = v;
    __syncthreads();
    #pragma unroll
    for (int off = 1; off < 256; off <<= 1) {
        int t = (threadIdx.x >= off) ? sm[threadIdx.x - off] : 0;
        __syncthreads();
        sm[threadIdx.x] += t;
        __syncthreads();
    }
    if (gid < N) rs[gid] = sm[threadIdx.x] - v;
    if (threadIdx.x == 255) bsum[blockIdx.x] = sm[255];
}

__global__ void k_scan2(int* bsum, int nb) {
    __shared__ int sm[512];
    int t = threadIdx.x;
    int v = (t < nb) ? bsum[t] : 0;
    sm[t] = v;
    __syncthreads();
    #pragma unroll
    for (int off = 1; off < 512; off <<= 1) {
        int u = (t >= off) ? sm[t - off] : 0;
        __syncthreads();
        sm[t] += u;
        __syncthreads();
    }
    if (t < nb) bsum[t] = sm[t] - v;
}

__global__ void k_scan3(int* rs, const int* __restrict__ bsum, int N, int E) {
    int gid = blockIdx.x * 256 + threadIdx.x;
    if (gid < N) rs[gid] += bsum[gid >> 8];
    if (gid == N) rs[N] = E;
}

__global__ void k_scatter(const int* __restrict__ ei, const float* __restrict__ attr,
                          const int* __restrict__ rs, const int* __restrict__ rank_,
                          int2* __restrict__ epack, int E) {
    int e = blockIdx.x * 256 + threadIdx.x;
    if (e < E) {
        int s = ei[e], d = ei[E + e];
        int p = rs[d] + rank_[e];
        epack[p] = make_int2(s, __float_as_int(attr[e]));
    }
}

// ------- aggregation: 16 lanes/edge, uint4 bf16 gathers, eb-folded table -------
// table T = h + eenc_b; msg = relu(fma(a, w, T_src)); self = sc*T[n] - sc*eenc_b
__device__ __forceinline__ void acc_edge(float acc[8], const uint4& u, float at,
        const float4& wa, const float4& wb) {
    acc[0] += fmaxf(fmaf(at, wa.x, bf2f(u.x & 0xFFFFu)), 0.f);
    acc[1] += fmaxf(fmaf(at, wa.y, bf2f_hi(u.x)), 0.f);
    acc[2] += fmaxf(fmaf(at, wa.z, bf2f(u.y & 0xFFFFu)), 0.f);
    acc[3] += fmaxf(fmaf(at, wa.w, bf2f_hi(u.y)), 0.f);
    acc[4] += fmaxf(fmaf(at, wb.x, bf2f(u.z & 0xFFFFu)), 0.f);
    acc[5] += fmaxf(fmaf(at, wb.y, bf2f_hi(u.z)), 0.f);
    acc[6] += fmaxf(fmaf(at, wb.z, bf2f(u.w & 0xFFFFu)), 0.f);
    acc[7] += fmaxf(fmaf(at, wb.w, bf2f_hi(u.w)), 0.f);
}

__global__ __launch_bounds__(256) void k_agg(
    const ushort_t* __restrict__ hb, const int* __restrict__ rs,
    const int2* __restrict__ epack,
    const float* __restrict__ ew, const float* __restrict__ ebv,
    const float* __restrict__ epsp, ushort_t* __restrict__ zb, int N) {
    int wave = (blockIdx.x * 256 + threadIdx.x) >> 6;
    if (wave >= N) return;
    int lane = threadIdx.x & 63;
    int p = lane >> 4;          // quarter-wave: edges j ≡ p (mod 4)
    int q = lane & 15;          // features 8q..8q+7
    int n = wave;
    int beg = rs[n];
    int cntE = rs[n + 1] - beg;
    float4 wa = ((const float4*)ew)[2 * q], wb = ((const float4*)ew)[2 * q + 1];

    float acc[8] = {0.f, 0.f, 0.f, 0.f, 0.f, 0.f, 0.f, 0.f};
    float acc2[8] = {0.f, 0.f, 0.f, 0.f, 0.f, 0.f, 0.f, 0.f};
    int j = p;
    for (; j + 4 < cntE; j += 8) {
        int2 e1 = epack[beg + j];
        int2 e2 = epack[beg + j + 4];
        uint4 u1 = *(const uint4*)(hb + (size_t)e1.x * HDIM + q * 8);
        uint4 u2 = *(const uint4*)(hb + (size_t)e2.x * HDIM + q * 8);
        acc_edge(acc,  u1, __int_as_float(e1.y), wa, wb);
        acc_edge(acc2, u2, __int_as_float(e2.y), wa, wb);
    }
    if (j < cntE) {
        int2 e1 = epack[beg + j];
        uint4 u1 = *(const uint4*)(hb + (size_t)e1.x * HDIM + q * 8);
        acc_edge(acc, u1, __int_as_float(e1.y), wa, wb);
    }
    #pragma unroll
    for (int k = 0; k < 8; ++k) {
        float v = acc[k] + acc2[k];
        v += __shfl_xor(v, 16);
        v += __shfl_xor(v, 32);
        acc[k] = v;
    }
    if (p == 0) {
        float sc = 1.f + epsp[0];
        float4 ba = ((const float4*)ebv)[2 * q], bb = ((const float4*)ebv)[2 * q + 1];
        float s0 = sc * ba.x, s1 = sc * ba.y, s2 = sc * ba.z, s3 = sc * ba.w;
        float s4 = sc * bb.x, s5 = sc * bb.y, s6 = sc * bb.z, s7 = sc * bb.w;
        uint4 u = *(const uint4*)(hb + (size_t)n * HDIM + q * 8);
        uint4 ob;
        ob.x = pack2(fmaf(sc, bf2f(u.x & 0xFFFFu), acc[0]) - s0,
                     fmaf(sc, bf2f_hi(u.x),        acc[1]) - s1);
        ob.y = pack2(fmaf(sc, bf2f(u.y & 0xFFFFu), acc[2]) - s2,
                     fmaf(sc, bf2f_hi(u.y),        acc[3]) - s3);
        ob.z = pack2(fmaf(sc, bf2f(u.z & 0xFFFFu), acc[4]) - s4,
                     fmaf(sc, bf2f_hi(u.z),        acc[5]) - s5);
        ob.w = pack2(fmaf(sc, bf2f(u.w & 0xFFFFu), acc[6]) - s6,
                     fmaf(sc, bf2f_hi(u.w),        acc[7]) - s7);
        *(uint4*)(zb + (size_t)n * HDIM + q * 8) = ob;
    }
}

// ------------- MFMA GEMM: out = epilogue(A @ W + bias), 256 rows/block -------------
// MODE 0: relu.  MODE 1: BN+relu.  EBF 1: add eenc_b (produce next gather table).
// WT = pre-transposed bf16 weights [n*WTPAD+k].
template<int MODE, int EBF>
__global__ __launch_bounds__(256) void k_gemm(
    const ushort_t* __restrict__ A, const ushort_t* __restrict__ WT,
    const float* __restrict__ bias, const float* __restrict__ gam,
    const float* __restrict__ bet, const float* __restrict__ ebe,
    ushort_t* __restrict__ out, int N) {
    __shared__ ushort_t wt[128 * WTPAD];
    int tid = threadIdx.x;
    #pragma unroll
    for (int i = 0; i < 9; ++i) {           // 128*136/8 = 2176 bf16x8 chunks
        int c = i * 256 + tid;
        if (c < 2176) ((bf16x8*)wt)[c] = ((const bf16x8*)WT)[c];
    }
    __syncthreads();

    int wid = tid >> 6, lane = tid & 63;
    int ra = lane & 15, qa = lane >> 4;

    bf16x8 bfr[4][8];
    #pragma unroll
    for (int ks = 0; ks < 4; ++ks)
        #pragma unroll
        for (int nf = 0; nf < 8; ++nf)
            bfr[ks][nf] = *(const bf16x8*)&wt[(nf * 16 + ra) * WTPAD + ks * 32 + qa * 8];

    float bi[8], gg[8], be_[8], ef[8];
    #pragma unroll
    for (int nf = 0; nf < 8; ++nf) {
        int col = nf * 16 + ra;
        bi[nf] = bias[col];
        if (MODE == 1) { gg[nf] = gam[col]; be_[nf] = bet[col]; }
        if (EBF)       { ef[nf] = ebe[col]; }
    }

    bf16x8 azero;
    #pragma unroll
    for (int j = 0; j < 8; ++j) azero[j] = 0;

    #pragma unroll
    for (int it = 0; it < 4; ++it) {
        int m0 = blockIdx.x * 256 + it * 64 + wid * 16;
        int mr = m0 + ra;
        bf16x8 afr[4];
        #pragma unroll
        for (int ks = 0; ks < 4; ++ks)
            afr[ks] = (mr < N) ? *(const bf16x8*)&A[(size_t)mr * HDIM + ks * 32 + qa * 8]
                               : azero;
        f32x4 acc[8];
        #pragma unroll
        for (int nf = 0; nf < 8; ++nf)
            #pragma unroll
            for (int j = 0; j < 4; ++j) acc[nf][j] = 0.f;
        #pragma unroll
        for (int ks = 0; ks < 4; ++ks)
            #pragma unroll
            for (int nf = 0; nf < 8; ++nf)
                acc[nf] = __builtin_amdgcn_mfma_f32_16x16x32_bf16(afr[ks], bfr[ks][nf], acc[nf], 0, 0, 0);
        #pragma unroll
        for (int nf = 0; nf < 8; ++nf) {
            #pragma unroll
            for (int r = 0; r < 4; ++r) {
                int row = m0 + qa * 4 + r;
                if (row < N) {
                    float v = acc[nf][r] + bi[nf];
                    if (MODE == 0) v = fmaxf(v, 0.f);
                    else           v = fmaxf(fmaf(gg[nf] * v, INVSTD, be_[nf]), 0.f);
                    if (EBF)       v += ef[nf];
                    out[(size_t)row * HDIM + nf * 16 + ra] = (ushort_t)f2bf(v);
                }
            }
        }
    }
}

// ------------- pooling: segmented reduction over sorted batch (bf16 in) -------------
#define PCHUNK 256
#define PWIN 4
__global__ __launch_bounds__(256) void k_pool2(const ushort_t* __restrict__ hb,
                                               const int* __restrict__ batch,
                                               float* pooled, int N) {
    __shared__ float acc[PWIN][HDIM];
    int n0 = blockIdx.x * PCHUNK;
    if (n0 >= N) return;
    int n1 = min(n0 + PCHUNK, N);
    int g0 = batch[n0];
    int g1 = batch[n1 - 1];
    for (int i = threadIdx.x; i < PWIN * HDIM; i += 256) ((float*)acc)[i] = 0.f;
    __syncthreads();

    int grp = threadIdx.x >> 5;
    int q = threadIdx.x & 31;
    float4 racc = make_float4(0.f, 0.f, 0.f, 0.f);
    int gcur = g0;
    for (int n = n0 + grp; n < n1; n += 8) {
        int g = batch[n];
        if (g != gcur) {
            int w = gcur - g0;
            float* p = (w < PWIN) ? &acc[w][q * 4] : (pooled + gcur * HDIM + q * 4);
            atomicAdd(p + 0, racc.x); atomicAdd(p + 1, racc.y);
            atomicAdd(p + 2, racc.z); atomicAdd(p + 3, racc.w);
            racc = make_float4(0.f, 0.f, 0.f, 0.f);
            gcur = g;
        }
        uint2 u = ((const uint2*)(hb + (size_t)n * HDIM))[q];
        racc.x += bf2f(u.x);
        racc.y += bf2f_hi(u.x);
        racc.z += bf2f(u.y);
        racc.w += bf2f_hi(u.y);
    }
    {
        int w = gcur - g0;
        float* p = (w < PWIN) ? &acc[w][q * 4] : (pooled + gcur * HDIM + q * 4);
        atomicAdd(p + 0, racc.x); atomicAdd(p + 1, racc.y);
        atomicAdd(p + 2, racc.z); atomicAdd(p + 3, racc.w);
    }
    __syncthreads();

    int span = min(g1 - g0 + 1, PWIN);
    for (int i = threadIdx.x; i < span * HDIM; i += 256) {
        int w = i >> 7, f = i & 127;
        float v = acc[w][f];
        if (v != 0.f) atomicAdd(pooled + (g0 + w) * HDIM + f, v);
    }
}

// ------------- classifier (count fused via binary search) -------------
__global__ void k_classify(const float* __restrict__ pooled, const int* __restrict__ batch,
                           const float* __restrict__ cw1, const float* __restrict__ cb1,
                           const float* __restrict__ cw2, const float* __restrict__ cb2,
                           float* __restrict__ out, int N) {
    __shared__ float p[HDIM];
    int g = blockIdx.x, j = threadIdx.x;
    int lo = 0, hi = N;
    while (lo < hi) { int m = (lo + hi) >> 1; if (batch[m] < g) lo = m + 1; else hi = m; }
    int lo2 = lo, hi2 = N;
    while (lo2 < hi2) { int m = (lo2 + hi2) >> 1; if (batch[m] < g + 1) lo2 = m + 1; else hi2 = m; }
    float c = fmaxf((float)(lo2 - lo), 1.f);
    p[j]      = pooled[g * HDIM + j] / c;
    p[j + 64] = pooled[g * HDIM + j + 64] / c;
    __syncthreads();
    float acc = cb1[j];
    #pragma unroll 4
    for (int k = 0; k < HDIM; ++k) acc = fmaf(p[k], cw1[k * 64 + j], acc);
    acc = fmaxf(acc, 0.f);
    float v = acc * cw2[j];
    #pragma unroll
    for (int off = 32; off > 0; off >>= 1) v += __shfl_down(v, off, 64);
    if (j == 0) out[g] = 1.f / (1.f + expf(-(v + cb2[0])));
}

static inline size_t align_up(size_t v, size_t a) { return (v + a - 1) & ~(a - 1); }

extern "C" void kernel_launch(void* const* d_in, const int* in_sizes, int n_in,
                              void* d_out, int out_size, void* d_ws, size_t ws_size,
                              hipStream_t stream) {
    const float* x      = (const float*)d_in[0];
    const int*   ei     = (const int*)d_in[1];
    const float* eattr  = (const float*)d_in[2];
    const int*   batch  = (const int*)d_in[3];
    const float* enc_w  = (const float*)d_in[4];
    const float* enc_b  = (const float*)d_in[5];
    const float* eenc_w = (const float*)d_in[6];
    const float* eenc_b = (const float*)d_in[7];
    const float* eps    = (const float*)d_in[8];
    const float* w1     = (const float*)d_in[9];
    const float* b1     = (const float*)d_in[10];
    const float* w2     = (const float*)d_in[11];
    const float* b2     = (const float*)d_in[12];
    const float* gamma  = (const float*)d_in[13];
    const float* beta   = (const float*)d_in[14];
    const float* cw1    = (const float*)d_in[15];
    const float* cb1    = (const float*)d_in[16];
    const float* cw2    = (const float*)d_in[17];
    const float* cb2    = (const float*)d_in[18];

    int N = in_sizes[0];          // 100000
    int E = in_sizes[2];          // 1600000

    char* wsb = (char*)d_ws;
    size_t off = 0;
    ushort_t* hb  = (ushort_t*)(wsb + off); off = align_up(off + (size_t)N * HDIM * 2, 256);
    ushort_t* zb  = (ushort_t*)(wsb + off); off = align_up(off + (size_t)N * HDIM * 2, 256);
    ushort_t* wtg = (ushort_t*)(wsb + off); off = align_up(off + (size_t)4 * WSLOT * 2, 256);
    float* pooled = (float*)(wsb + off);    off = align_up(off + NGRAPH * HDIM * 4, 256);
    int*   deg    = (int*)(wsb + off);      off = align_up(off + (size_t)N * 4, 256);
    int*   rs     = (int*)(wsb + off);      off = align_up(off + (size_t)(N + 1) * 4, 256);
    int*   rank_  = (int*)(wsb + off);      off = align_up(off + (size_t)E * 4, 256);
    int*   bsum   = (int*)(wsb + off);      off = align_up(off + 2048 * 4, 256);
    int2*  epack  = (int2*)(wsb + off);     off = align_up(off + (size_t)E * 8, 256);

    int nb = (N + 255) / 256;
    int eb_blocks = (E + 255) / 256;

    // CSR build + weight prep
    hipMemsetAsync(deg, 0, (size_t)N * 4, stream);
    k_hist<<<eb_blocks, 256, 0, stream>>>(ei, deg, rank_, E);
    k_prepw<<<256, 256, 0, stream>>>(w1, w2, wtg);
    k_scan1<<<nb, 256, 0, stream>>>(deg, rs, bsum, N);
    k_scan2<<<1, 512, 0, stream>>>(bsum, nb);
    k_scan3<<<(N + 256) / 256, 256, 0, stream>>>(rs, bsum, N, E);
    k_scatter<<<eb_blocks, 256, 0, stream>>>(ei, eattr, rs, rank_, epack, E);

    hipMemsetAsync(pooled, 0, NGRAPH * HDIM * sizeof(float), stream);
    k_encode<<<2048, 256, 0, stream>>>(x, enc_w, enc_b, eenc_b, hb, N);

    int gblocks = (N + 255) / 256;
    int ablocks = (N * 64 + 255) / 256;

    // layer 0 (gather tables carry +eenc_b; agg corrects self-term)
    k_agg<<<ablocks, 256, 0, stream>>>(hb, rs, epack, eenc_w, eenc_b, eps + 0, zb, N);
    k_gemm<0,0><<<gblocks, 256, 0, stream>>>(zb, wtg + 0 * WSLOT, b1, nullptr, nullptr,
                                             nullptr, zb, N);
    k_gemm<1,1><<<gblocks, 256, 0, stream>>>(zb, wtg + 1 * WSLOT, b2, gamma, beta,
                                             eenc_b, hb, N);
    // layer 1 (final output plain: only pooled)
    k_agg<<<ablocks, 256, 0, stream>>>(hb, rs, epack, eenc_w, eenc_b, eps + 1, zb, N);
    k_gemm<0,0><<<gblocks, 256, 0, stream>>>(zb, wtg + 2 * WSLOT, b1 + HDIM, nullptr, nullptr,
                                             nullptr, zb, N);
    k_gemm<1,0><<<gblocks, 256, 0, stream>>>(zb, wtg + 3 * WSLOT, b2 + HDIM, gamma + HDIM,
                                             beta + HDIM, nullptr, hb, N);

    k_pool2<<<(N + PCHUNK - 1) / PCHUNK, 256, 0, stream>>>(hb, batch, pooled, N);
    k_classify<<<NGRAPH, 64, 0, stream>>>(pooled, batch, cw1, cb1, cw2, cb2, (float*)d_out, N);
}

// Round 11
// 330.064 us; speedup vs baseline: 1.3670x; 1.0341x over previous
//
#include <hip/hip_runtime.h>

#define HDIM 128
#define NGRAPH 64
#define INVSTD 0.99999500003749972f   // 1/sqrt(1+1e-5)
#define WTPAD 136
#define WSLOT (128 * WTPAD)

typedef unsigned short ushort_t;
typedef unsigned int uint_t;
typedef unsigned char uchar_t;
typedef __attribute__((ext_vector_type(8))) short bf16x8;   // 8 bf16 = 4 VGPR
typedef __attribute__((ext_vector_type(4))) float f32x4;
typedef __attribute__((ext_vector_type(2))) float f32x2;

__device__ __forceinline__ float bf2f(uint_t u) {            // low 16 bits
    return __int_as_float((int)(u << 16));
}
__device__ __forceinline__ float bf2f_hi(uint_t u) {
    return __int_as_float((int)(u & 0xFFFF0000u));
}
__device__ __forceinline__ uint_t f2bf(float f) {            // RNE
    uint_t x = __float_as_uint(f);
    return (x + 0x7FFFu + ((x >> 16) & 1u)) >> 16;
}
__device__ __forceinline__ uint_t pack2(float a, float b) {
    return f2bf(a) | (f2bf(b) << 16);
}
__device__ __forceinline__ uint_t pack4fp8(float a, float b, float c, float d) {
    int v = __builtin_amdgcn_cvt_pk_fp8_f32(a, b, 0, false);
    v = __builtin_amdgcn_cvt_pk_fp8_f32(c, d, v, true);
    return (uint_t)v;
}

// ---- encode: table T = x*ew + enc_b + eenc_b; hb = bf16(T), hq = fp8(T)
__global__ void k_encode(const float* __restrict__ x, const float* __restrict__ ew,
                         const float* __restrict__ enb, const float* __restrict__ ebe,
                         ushort_t* __restrict__ hb, uchar_t* __restrict__ hq, int N) {
    int tid = blockIdx.x * blockDim.x + threadIdx.x;
    int stride = gridDim.x * blockDim.x;
    int q = tid & 15;
    float4 wa = ((const float4*)ew)[2 * q];
    float4 wb = ((const float4*)ew)[2 * q + 1];
    float4 ba = ((const float4*)enb)[2 * q];
    float4 bb = ((const float4*)enb)[2 * q + 1];
    float4 ea = ((const float4*)ebe)[2 * q];
    float4 eb2 = ((const float4*)ebe)[2 * q + 1];
    ba.x += ea.x; ba.y += ea.y; ba.z += ea.z; ba.w += ea.w;
    bb.x += eb2.x; bb.y += eb2.y; bb.z += eb2.z; bb.w += eb2.w;
    int total = N * 16;
    for (int t = tid; t < total; t += stride) {
        int n = t >> 4;
        float xv = x[n];
        float v0 = fmaf(xv, wa.x, ba.x), v1 = fmaf(xv, wa.y, ba.y);
        float v2 = fmaf(xv, wa.z, ba.z), v3 = fmaf(xv, wa.w, ba.w);
        float v4 = fmaf(xv, wb.x, bb.x), v5 = fmaf(xv, wb.y, bb.y);
        float v6 = fmaf(xv, wb.z, bb.z), v7 = fmaf(xv, wb.w, bb.w);
        uint4 o;
        o.x = pack2(v0, v1); o.y = pack2(v2, v3);
        o.z = pack2(v4, v5); o.w = pack2(v6, v7);
        ((uint4*)(hb + (size_t)n * HDIM))[q] = o;
        uint2 o8;
        o8.x = pack4fp8(v0, v1, v2, v3);
        o8.y = pack4fp8(v4, v5, v6, v7);
        ((uint2*)(hq + (size_t)n * HDIM))[q] = o8;
    }
}

// ---- weight prep: wtg[slot][n*WTPAD+k] = bf16(W_slot[k][n]); slots {w1_0,w2_0,w1_1,w2_1}
__global__ void k_prepw(const float* __restrict__ w1, const float* __restrict__ w2,
                        ushort_t* __restrict__ wtg) {
    int t = blockIdx.x * 256 + threadIdx.x;
    if (t >= 4 * 16384) return;
    int w = t >> 14, idx = t & 16383;
    int k = idx >> 7, n = idx & 127;
    const float* src = ((w & 1) ? w2 : w1) + (size_t)(w >> 1) * 16384;
    wtg[(size_t)w * WSLOT + n * WTPAD + k] = (ushort_t)f2bf(src[idx]);
}

// ---------------- CSR build ----------------
__global__ void k_hist(const int* __restrict__ ei, int* deg, int* __restrict__ rank_, int E) {
    int e = blockIdx.x * 256 + threadIdx.x;
    if (e < E) {
        int d = ei[E + e];
        rank_[e] = atomicAdd(&deg[d], 1);
    }
}

__global__ void k_scan1(const int* __restrict__ deg, int* rs, int* bsum, int N) {
    __shared__ int sm[256];
    int gid = blockIdx.x * 256 + threadIdx.x;
    int v = (gid < N) ? deg[gid] : 0;
    sm[threadIdx.x] = v;
    __syncthreads();
    #pragma unroll
    for (int off = 1; off < 256; off <<= 1) {
        int t = (threadIdx.x >= off) ? sm[threadIdx.x - off] : 0;
        __syncthreads();
        sm[threadIdx.x] += t;
        __syncthreads();
    }
    if (gid < N) rs[gid] = sm[threadIdx.x] - v;
    if (threadIdx.x == 255) bsum[blockIdx.x] = sm[255];
}

__global__ void k_scan2(int* bsum, int nb) {
    __shared__ int sm[512];
    int t = threadIdx.x;
    int v = (t < nb) ? bsum[t] : 0;
    sm[t] = v;
    __syncthreads();
    #pragma unroll
    for (int off = 1; off < 512; off <<= 1) {
        int u = (t >= off) ? sm[t - off] : 0;
        __syncthreads();
        sm[t] += u;
        __syncthreads();
    }
    if (t < nb) bsum[t] = sm[t] - v;
}

__global__ void k_scan3(int* rs, const int* __restrict__ bsum, int N, int E) {
    int gid = blockIdx.x * 256 + threadIdx.x;
    if (gid < N) rs[gid] += bsum[gid >> 8];
    if (gid == N) rs[N] = E;
}

__global__ void k_scatter(const int* __restrict__ ei, const float* __restrict__ attr,
                          const int* __restrict__ rs, const int* __restrict__ rank_,
                          int2* __restrict__ epack, int E) {
    int e = blockIdx.x * 256 + threadIdx.x;
    if (e < E) {
        int s = ei[e], d = ei[E + e];
        int p = rs[d] + rank_[e];
        epack[p] = make_int2(s, __float_as_int(attr[e]));
    }
}

// ------- aggregation: 16 lanes/edge, fp8 uint2 gathers, eb-folded table -------
// msg = relu(fma(a, w, Tq_src)); self = sc*Tb[n] - sc*eenc_b
__device__ __forceinline__ void acc_edge(float acc[8], const uint2& u, float at,
        const float4& wa, const float4& wb) {
    f32x2 p0 = __builtin_amdgcn_cvt_pk_f32_fp8(u.x, false);
    f32x2 p1 = __builtin_amdgcn_cvt_pk_f32_fp8(u.x, true);
    f32x2 p2 = __builtin_amdgcn_cvt_pk_f32_fp8(u.y, false);
    f32x2 p3 = __builtin_amdgcn_cvt_pk_f32_fp8(u.y, true);
    acc[0] += fmaxf(fmaf(at, wa.x, p0[0]), 0.f);
    acc[1] += fmaxf(fmaf(at, wa.y, p0[1]), 0.f);
    acc[2] += fmaxf(fmaf(at, wa.z, p1[0]), 0.f);
    acc[3] += fmaxf(fmaf(at, wa.w, p1[1]), 0.f);
    acc[4] += fmaxf(fmaf(at, wb.x, p2[0]), 0.f);
    acc[5] += fmaxf(fmaf(at, wb.y, p2[1]), 0.f);
    acc[6] += fmaxf(fmaf(at, wb.z, p3[0]), 0.f);
    acc[7] += fmaxf(fmaf(at, wb.w, p3[1]), 0.f);
}

__global__ __launch_bounds__(256) void k_agg(
    const uchar_t* __restrict__ hq, const ushort_t* __restrict__ hb,
    const int* __restrict__ rs, const int2* __restrict__ epack,
    const float* __restrict__ ew, const float* __restrict__ ebv,
    const float* __restrict__ epsp, ushort_t* __restrict__ zb, int N) {
    int wave = (blockIdx.x * 256 + threadIdx.x) >> 6;
    if (wave >= N) return;
    int lane = threadIdx.x & 63;
    int p = lane >> 4;          // quarter-wave: edges j ≡ p (mod 4)
    int q = lane & 15;          // features 8q..8q+7
    int n = wave;
    int beg = rs[n];
    int cntE = rs[n + 1] - beg;
    float4 wa = ((const float4*)ew)[2 * q], wb = ((const float4*)ew)[2 * q + 1];

    float acc[8] = {0.f, 0.f, 0.f, 0.f, 0.f, 0.f, 0.f, 0.f};
    float acc2[8] = {0.f, 0.f, 0.f, 0.f, 0.f, 0.f, 0.f, 0.f};
    int j = p;
    for (; j + 4 < cntE; j += 8) {
        int2 e1 = epack[beg + j];
        int2 e2 = epack[beg + j + 4];
        uint2 u1 = *(const uint2*)(hq + (size_t)e1.x * HDIM + q * 8);
        uint2 u2 = *(const uint2*)(hq + (size_t)e2.x * HDIM + q * 8);
        acc_edge(acc,  u1, __int_as_float(e1.y), wa, wb);
        acc_edge(acc2, u2, __int_as_float(e2.y), wa, wb);
    }
    if (j < cntE) {
        int2 e1 = epack[beg + j];
        uint2 u1 = *(const uint2*)(hq + (size_t)e1.x * HDIM + q * 8);
        acc_edge(acc, u1, __int_as_float(e1.y), wa, wb);
    }
    #pragma unroll
    for (int k = 0; k < 8; ++k) {
        float v = acc[k] + acc2[k];
        v += __shfl_xor(v, 16);
        v += __shfl_xor(v, 32);
        acc[k] = v;
    }
    if (p == 0) {
        float sc = 1.f + epsp[0];
        float4 ba = ((const float4*)ebv)[2 * q], bb = ((const float4*)ebv)[2 * q + 1];
        float s0 = sc * ba.x, s1 = sc * ba.y, s2 = sc * ba.z, s3 = sc * ba.w;
        float s4 = sc * bb.x, s5 = sc * bb.y, s6 = sc * bb.z, s7 = sc * bb.w;
        uint4 u = *(const uint4*)(hb + (size_t)n * HDIM + q * 8);
        uint4 ob;
        ob.x = pack2(fmaf(sc, bf2f(u.x & 0xFFFFu), acc[0]) - s0,
                     fmaf(sc, bf2f_hi(u.x),        acc[1]) - s1);
        ob.y = pack2(fmaf(sc, bf2f(u.y & 0xFFFFu), acc[2]) - s2,
                     fmaf(sc, bf2f_hi(u.y),        acc[3]) - s3);
        ob.z = pack2(fmaf(sc, bf2f(u.z & 0xFFFFu), acc[4]) - s4,
                     fmaf(sc, bf2f_hi(u.z),        acc[5]) - s5);
        ob.w = pack2(fmaf(sc, bf2f(u.w & 0xFFFFu), acc[6]) - s6,
                     fmaf(sc, bf2f_hi(u.w),        acc[7]) - s7);
        *(uint4*)(zb + (size_t)n * HDIM + q * 8) = ob;
    }
}

// ------------- MFMA GEMM: out = epilogue(A @ W + bias), 256 rows/block -------------
// MODE 0: relu.  MODE 1: BN+relu.  EBF 1: +eenc_b (next gather table).  WQ 1: fp8 copy.
template<int MODE, int EBF, int WQ>
__global__ __launch_bounds__(256) void k_gemm(
    const ushort_t* __restrict__ A, const ushort_t* __restrict__ WT,
    const float* __restrict__ bias, const float* __restrict__ gam,
    const float* __restrict__ bet, const float* __restrict__ ebe,
    ushort_t* __restrict__ out, uchar_t* __restrict__ outq, int N) {
    __shared__ ushort_t wt[128 * WTPAD];
    int tid = threadIdx.x;
    #pragma unroll
    for (int i = 0; i < 9; ++i) {           // 128*136/8 = 2176 bf16x8 chunks
        int c = i * 256 + tid;
        if (c < 2176) ((bf16x8*)wt)[c] = ((const bf16x8*)WT)[c];
    }
    __syncthreads();

    int wid = tid >> 6, lane = tid & 63;
    int ra = lane & 15, qa = lane >> 4;

    bf16x8 bfr[4][8];
    #pragma unroll
    for (int ks = 0; ks < 4; ++ks)
        #pragma unroll
        for (int nf = 0; nf < 8; ++nf)
            bfr[ks][nf] = *(const bf16x8*)&wt[(nf * 16 + ra) * WTPAD + ks * 32 + qa * 8];

    float bi[8], gg[8], be_[8], ef[8];
    #pragma unroll
    for (int nf = 0; nf < 8; ++nf) {
        int col = nf * 16 + ra;
        bi[nf] = bias[col];
        if (MODE == 1) { gg[nf] = gam[col]; be_[nf] = bet[col]; }
        if (EBF)       { ef[nf] = ebe[col]; }
    }

    bf16x8 azero;
    #pragma unroll
    for (int j = 0; j < 8; ++j) azero[j] = 0;

    #pragma unroll
    for (int it = 0; it < 4; ++it) {
        int m0 = blockIdx.x * 256 + it * 64 + wid * 16;
        int mr = m0 + ra;
        bf16x8 afr[4];
        #pragma unroll
        for (int ks = 0; ks < 4; ++ks)
            afr[ks] = (mr < N) ? *(const bf16x8*)&A[(size_t)mr * HDIM + ks * 32 + qa * 8]
                               : azero;
        f32x4 acc[8];
        #pragma unroll
        for (int nf = 0; nf < 8; ++nf)
            #pragma unroll
            for (int j = 0; j < 4; ++j) acc[nf][j] = 0.f;
        #pragma unroll
        for (int ks = 0; ks < 4; ++ks)
            #pragma unroll
            for (int nf = 0; nf < 8; ++nf)
                acc[nf] = __builtin_amdgcn_mfma_f32_16x16x32_bf16(afr[ks], bfr[ks][nf], acc[nf], 0, 0, 0);
        #pragma unroll
        for (int nf = 0; nf < 8; ++nf) {
            #pragma unroll
            for (int r = 0; r < 4; ++r) {
                int row = m0 + qa * 4 + r;
                if (row < N) {
                    float v = acc[nf][r] + bi[nf];
                    if (MODE == 0) v = fmaxf(v, 0.f);
                    else           v = fmaxf(fmaf(gg[nf] * v, INVSTD, be_[nf]), 0.f);
                    if (EBF)       v += ef[nf];
                    out[(size_t)row * HDIM + nf * 16 + ra] = (ushort_t)f2bf(v);
                    if (WQ)
                        outq[(size_t)row * HDIM + nf * 16 + ra] =
                            (uchar_t)(__builtin_amdgcn_cvt_pk_fp8_f32(v, 0.f, 0, false) & 0xFF);
                }
            }
        }
    }
}

// ------------- pooling: segmented reduction over sorted batch (bf16 in) -------------
#define PCHUNK 256
#define PWIN 4
__global__ __launch_bounds__(256) void k_pool2(const ushort_t* __restrict__ hb,
                                               const int* __restrict__ batch,
                                               float* pooled, int N) {
    __shared__ float acc[PWIN][HDIM];
    int n0 = blockIdx.x * PCHUNK;
    if (n0 >= N) return;
    int n1 = min(n0 + PCHUNK, N);
    int g0 = batch[n0];
    int g1 = batch[n1 - 1];
    for (int i = threadIdx.x; i < PWIN * HDIM; i += 256) ((float*)acc)[i] = 0.f;
    __syncthreads();

    int grp = threadIdx.x >> 5;
    int q = threadIdx.x & 31;
    float4 racc = make_float4(0.f, 0.f, 0.f, 0.f);
    int gcur = g0;
    for (int n = n0 + grp; n < n1; n += 8) {
        int g = batch[n];
        if (g != gcur) {
            int w = gcur - g0;
            float* p = (w < PWIN) ? &acc[w][q * 4] : (pooled + gcur * HDIM + q * 4);
            atomicAdd(p + 0, racc.x); atomicAdd(p + 1, racc.y);
            atomicAdd(p + 2, racc.z); atomicAdd(p + 3, racc.w);
            racc = make_float4(0.f, 0.f, 0.f, 0.f);
            gcur = g;
        }
        uint2 u = ((const uint2*)(hb + (size_t)n * HDIM))[q];
        racc.x += bf2f(u.x);
        racc.y += bf2f_hi(u.x);
        racc.z += bf2f(u.y);
        racc.w += bf2f_hi(u.y);
    }
    {
        int w = gcur - g0;
        float* p = (w < PWIN) ? &acc[w][q * 4] : (pooled + gcur * HDIM + q * 4);
        atomicAdd(p + 0, racc.x); atomicAdd(p + 1, racc.y);
        atomicAdd(p + 2, racc.z); atomicAdd(p + 3, racc.w);
    }
    __syncthreads();

    int span = min(g1 - g0 + 1, PWIN);
    for (int i = threadIdx.x; i < span * HDIM; i += 256) {
        int w = i >> 7, f = i & 127;
        float v = acc[w][f];
        if (v != 0.f) atomicAdd(pooled + (g0 + w) * HDIM + f, v);
    }
}

// ------------- classifier (count fused via binary search) -------------
__global__ void k_classify(const float* __restrict__ pooled, const int* __restrict__ batch,
                           const float* __restrict__ cw1, const float* __restrict__ cb1,
                           const float* __restrict__ cw2, const float* __restrict__ cb2,
                           float* __restrict__ out, int N) {
    __shared__ float p[HDIM];
    int g = blockIdx.x, j = threadIdx.x;
    int lo = 0, hi = N;
    while (lo < hi) { int m = (lo + hi) >> 1; if (batch[m] < g) lo = m + 1; else hi = m; }
    int lo2 = lo, hi2 = N;
    while (lo2 < hi2) { int m = (lo2 + hi2) >> 1; if (batch[m] < g + 1) lo2 = m + 1; else hi2 = m; }
    float c = fmaxf((float)(lo2 - lo), 1.f);
    p[j]      = pooled[g * HDIM + j] / c;
    p[j + 64] = pooled[g * HDIM + j + 64] / c;
    __syncthreads();
    float acc = cb1[j];
    #pragma unroll 4
    for (int k = 0; k < HDIM; ++k) acc = fmaf(p[k], cw1[k * 64 + j], acc);
    acc = fmaxf(acc, 0.f);
    float v = acc * cw2[j];
    #pragma unroll
    for (int off = 32; off > 0; off >>= 1) v += __shfl_down(v, off, 64);
    if (j == 0) out[g] = 1.f / (1.f + expf(-(v + cb2[0])));
}

static inline size_t align_up(size_t v, size_t a) { return (v + a - 1) & ~(a - 1); }

extern "C" void kernel_launch(void* const* d_in, const int* in_sizes, int n_in,
                              void* d_out, int out_size, void* d_ws, size_t ws_size,
                              hipStream_t stream) {
    const float* x      = (const float*)d_in[0];
    const int*   ei     = (const int*)d_in[1];
    const float* eattr  = (const float*)d_in[2];
    const int*   batch  = (const int*)d_in[3];
    const float* enc_w  = (const float*)d_in[4];
    const float* enc_b  = (const float*)d_in[5];
    const float* eenc_w = (const float*)d_in[6];
    const float* eenc_b = (const float*)d_in[7];
    const float* eps    = (const float*)d_in[8];
    const float* w1     = (const float*)d_in[9];
    const float* b1     = (const float*)d_in[10];
    const float* w2     = (const float*)d_in[11];
    const float* b2     = (const float*)d_in[12];
    const float* gamma  = (const float*)d_in[13];
    const float* beta   = (const float*)d_in[14];
    const float* cw1    = (const float*)d_in[15];
    const float* cb1    = (const float*)d_in[16];
    const float* cw2    = (const float*)d_in[17];
    const float* cb2    = (const float*)d_in[18];

    int N = in_sizes[0];          // 100000
    int E = in_sizes[2];          // 1600000

    char* wsb = (char*)d_ws;
    size_t off = 0;
    ushort_t* hb  = (ushort_t*)(wsb + off); off = align_up(off + (size_t)N * HDIM * 2, 256);
    uchar_t*  hq  = (uchar_t*)(wsb + off);  off = align_up(off + (size_t)N * HDIM, 256);
    ushort_t* zb  = (ushort_t*)(wsb + off); off = align_up(off + (size_t)N * HDIM * 2, 256);
    ushort_t* wtg = (ushort_t*)(wsb + off); off = align_up(off + (size_t)4 * WSLOT * 2, 256);
    float* pooled = (float*)(wsb + off);    off = align_up(off + NGRAPH * HDIM * 4, 256);
    int*   deg    = (int*)(wsb + off);      off = align_up(off + (size_t)N * 4, 256);
    int*   rs     = (int*)(wsb + off);      off = align_up(off + (size_t)(N + 1) * 4, 256);
    int*   rank_  = (int*)(wsb + off);      off = align_up(off + (size_t)E * 4, 256);
    int*   bsum   = (int*)(wsb + off);      off = align_up(off + 2048 * 4, 256);
    int2*  epack  = (int2*)(wsb + off);     off = align_up(off + (size_t)E * 8, 256);

    int nb = (N + 255) / 256;
    int eb_blocks = (E + 255) / 256;

    // CSR build + weight prep
    hipMemsetAsync(deg, 0, (size_t)N * 4, stream);
    k_hist<<<eb_blocks, 256, 0, stream>>>(ei, deg, rank_, E);
    k_prepw<<<256, 256, 0, stream>>>(w1, w2, wtg);
    k_scan1<<<nb, 256, 0, stream>>>(deg, rs, bsum, N);
    k_scan2<<<1, 512, 0, stream>>>(bsum, nb);
    k_scan3<<<(N + 256) / 256, 256, 0, stream>>>(rs, bsum, N, E);
    k_scatter<<<eb_blocks, 256, 0, stream>>>(ei, eattr, rs, rank_, epack, E);

    hipMemsetAsync(pooled, 0, NGRAPH * HDIM * sizeof(float), stream);
    k_encode<<<2048, 256, 0, stream>>>(x, enc_w, enc_b, eenc_b, hb, hq, N);

    int gblocks = (N + 255) / 256;
    int ablocks = (N * 64 + 255) / 256;

    // layer 0 (gather tables carry +eenc_b; agg corrects self-term)
    k_agg<<<ablocks, 256, 0, stream>>>(hq, hb, rs, epack, eenc_w, eenc_b, eps + 0, zb, N);
    k_gemm<0,0,0><<<gblocks, 256, 0, stream>>>(zb, wtg + 0 * WSLOT, b1, nullptr, nullptr,
                                               nullptr, zb, nullptr, N);
    k_gemm<1,1,1><<<gblocks, 256, 0, stream>>>(zb, wtg + 1 * WSLOT, b2, gamma, beta,
                                               eenc_b, hb, hq, N);
    // layer 1 (final output plain: only pooled)
    k_agg<<<ablocks, 256, 0, stream>>>(hq, hb, rs, epack, eenc_w, eenc_b, eps + 1, zb, N);
    k_gemm<0,0,0><<<gblocks, 256, 0, stream>>>(zb, wtg + 2 * WSLOT, b1 + HDIM, nullptr, nullptr,
                                               nullptr, zb, nullptr, N);
    k_gemm<1,0,0><<<gblocks, 256, 0, stream>>>(zb, wtg + 3 * WSLOT, b2 + HDIM, gamma + HDIM,
                                               beta + HDIM, nullptr, hb, nullptr, N);

    k_pool2<<<(N + PCHUNK - 1) / PCHUNK, 256, 0, stream>>>(hb, batch, pooled, N);
    k_classify<<<NGRAPH, 64, 0, stream>>>(pooled, batch, cw1, cb1, cw2, cb2, (float*)d_out, N);
}